// Round 6
// baseline (1506.389 us; speedup 1.0000x reference)
//
#include <hip/hip_runtime.h>

// GCN 2-layer, R19 = scatter-push rewrite. R18 post-mortem: row-pull gather is
// dependent-chain bound (2-3 x ~1200cy round trips per row; 22 waves can't
// hide it; 36 CU-cy/edge vs ~11 floor, no pipe >35%). New structure: per-
// bucket (64 dsts) edge-parallel LDS f32 scatter-accumulate (ds_add_f32):
//  - one coalesced bbuf load per 64 edges, readlane-broadcast -> SCALAR row
//    addresses, 16 independent row loads in flight, no per-row chains;
//  - pair-swap swizzle keeps ds_add at the 2-way bank floor;
//  - CSR build deleted (prep = deg+dinv+Xs only); both layers use scatter.
//   wswz(+ctrl zero) | bin | prep(dinv,Xs) | scat<0> -> P | mlp (in-place P) | scat<1> -> out
// Lessons: no global atomic work queues (R7); no serial stragglers (R9); zero
// ALL control memory (R11); min-waves must fit live regs (R14); don't hand-
// pipeline scattered PULL loads (R16); restructure for fat rows (R17); no
// serial dependent-load tails (R18); pull can't beat its chain latency -
// scatter-push converts latency-bound to throughput-bound (R19).

typedef short bf16x8 __attribute__((ext_vector_type(8)));
typedef float f32x4 __attribute__((ext_vector_type(4)));

#define LDSTRIDE 264   // H tile: 16 rows * 264 ushort = 528 B/row
#define BSHIFT 6       // 64 dsts per bucket
#define BMASK 63
#define ROWS 64
#define ACCSTR 132     // acc row stride in f32 (128 + 4 pad)

__device__ inline unsigned short f2bf(float f) {          // RNE
    unsigned int u = __float_as_uint(f);
    u += 0x7FFF + ((u >> 16) & 1);
    return (unsigned short)(u >> 16);
}
__device__ inline float bf2f(unsigned short h) {
    return __uint_as_float(((unsigned int)h) << 16);
}

// ---------- W swizzle into MFMA b-frag order + ctrl zero ----------
__device__ inline void swz1(const float* W, unsigned short* Ws, int K, int N, int i) {
    int k = i / N, n = i % N;
    int KC = K >> 5;
    size_t d = ((((size_t)(n >> 4) * KC + (k >> 5)) * 64) + ((k >> 3) & 3) * 16 + (n & 15)) * 8
               + (k & 7);
    Ws[d] = f2bf(W[i]);
}
__global__ void wswz_kernel(const float* __restrict__ W1, const float* __restrict__ W2,
                            unsigned short* __restrict__ W1s, unsigned short* __restrict__ W2s,
                            int* __restrict__ ctrl) {
    int i = blockIdx.x * blockDim.x + threadIdx.x;
    if (blockIdx.x == 0) {                     // zero ALL 1024 ctrl ints
        for (int j = threadIdx.x; j < 1024; j += 256) ctrl[j] = 0;
    }
    if (i < 32768) swz1(W1, W1s, 128, 256, i);
    else if (i < 65536) swz1(W2, W2s, 256, 128, i - 32768);
}

// ---------- pass 1: bin edges by dst>>6 (4 B packed) ----------
__global__ __launch_bounds__(256) void bin_kernel(
    const int* __restrict__ src, const int* __restrict__ dst,
    int* __restrict__ bcur, unsigned int* __restrict__ bbuf,
    int E, int cap, int nbuck) {
    __shared__ int cnt[1024];
    __shared__ int base[1024];
    int t = threadIdx.x;
    for (int i = t; i < nbuck; i += 256) cnt[i] = 0;
    __syncthreads();
    int e0 = blockIdx.x * 2048;
    unsigned int p_[8];
    int b_[8];
#pragma unroll
    for (int i = 0; i < 8; i++) {
        int e = e0 + i * 256 + t;
        if (e < E) {
            int s = src[e], d = dst[e];
            b_[i] = d >> BSHIFT;
            p_[i] = ((unsigned)(d & BMASK) << 24) | (unsigned)s;   // N < 2^24
            atomicAdd(&cnt[b_[i]], 1);
        } else b_[i] = -1;
    }
    __syncthreads();
    for (int b = t; b < nbuck; b += 256) {
        int c = cnt[b];
        base[b] = (c > 0) ? atomicAdd(&bcur[b], c) : 0;
    }
    __syncthreads();
    for (int i = t; i < nbuck; i += 256) cnt[i] = 0;   // reuse as cursor
    __syncthreads();
#pragma unroll
    for (int i = 0; i < 8; i++) {
        if (b_[i] >= 0) {
            int b = b_[i];
            int p = base[b] + atomicAdd(&cnt[b], 1);
            if (p >= 0 && p < cap) bbuf[(size_t)b * cap + p] = p_[i];
        }
    }
}

// ---------- pass 2: per-bucket deg -> dinv + fused Xs scale (no CSR) ----------
__global__ __launch_bounds__(256) void prep_kernel(
    const int* __restrict__ bcur, const unsigned int* __restrict__ bbuf,
    const float* __restrict__ x, float* __restrict__ dinv,
    unsigned short* __restrict__ Xs, int N, int cap) {
    __shared__ int ldeg[ROWS];
    __shared__ float sdv[ROWS];
    int b = blockIdx.x, t = threadIdx.x;
    int cnt = min(max(bcur[b], 0), cap);
    if (t < ROWS) ldeg[t] = 0;
    __syncthreads();
    const unsigned int* mybuf = bbuf + (size_t)b * cap;
    for (int i = t; i < cnt; i += 256)
        atomicAdd(&ldeg[mybuf[i] >> 24], 1);
    __syncthreads();
    if (t < ROWS) {
        int gr = b * ROWS + t;
        float dv = rsqrtf((float)ldeg[t] + 1.0f);      // self-loop adds 1
        sdv[t] = dv;
        if (gr < N) dinv[gr] = dv;
    }
    __syncthreads();
    int rbase = b * ROWS;
    for (int i = t; i < ROWS * 32; i += 256) {
        int rl = i >> 5;
        int gr = rbase + rl;
        if (gr >= N) break;
        float s = sdv[rl];
        float4 xv = ((const float4*)x)[(size_t)gr * 32 + (i & 31)];
        ushort4 o;
        o.x = f2bf(xv.x * s); o.y = f2bf(xv.y * s);
        o.z = f2bf(xv.z * s); o.w = f2bf(xv.w * s);
        ((ushort4*)Xs)[(size_t)gr * 32 + (i & 31)] = o;
    }
}

// ---------- scatter-aggregate per bucket: acc[dst][f] += IN[src][f] ----------
// Block 512 (8 waves) per 64-row bucket. Lane l owns feats (2l, 2l+1) of every
// row. Pair-swap swizzle: feat0 at slot 2l+bit, feat1 at 2l+1-bit (bit =
// (l>>4)&1) -> each ds_add instr hits 2-way banks (the 64-lane x 4B floor).
// Edge phase: stripe of 64 edges = ONE coalesced bbuf load; readlane gives
// SCALAR (src,dst); 16 row loads in flight, no dependent chains.
// MODE 0: out = bf16(sum * dinv) -> OP.  MODE 1: out = relu(sum*dinv+b) -> OF.
template <int MODE>
__global__ __launch_bounds__(512, 6) void scat_kernel(
    const int* __restrict__ bcur, const unsigned int* __restrict__ bbuf,
    const unsigned short* __restrict__ IN,
    const float* __restrict__ dinv, const float* __restrict__ bias,
    unsigned short* __restrict__ OP, float* __restrict__ OF,
    int N, int cap) {
    __shared__ float acc[ROWS * ACCSTR];   // 33792 B
    int b = blockIdx.x, t = threadIdx.x;
    int wave = t >> 6, l = t & 63;
    int cnt = min(max(bcur[b], 0), cap);
    int r0 = b * ROWS;
    int bit = (l >> 4) & 1;
    int off0 = 2 * l + bit;
    int off1 = 2 * l + 1 - bit;

    // ---- init with self-loop row (8 rows per wave) ----
#pragma unroll
    for (int q = 0; q < 8; q++) {
        int lr = wave * 8 + q;
        int gr = r0 + lr;
        int rc = gr < N ? gr : N - 1;
        unsigned d = ((const unsigned*)(IN + (size_t)rc * 128))[l];
        acc[lr * ACCSTR + off0] = bf2f((unsigned short)(d & 0xffffu));
        acc[lr * ACCSTR + off1] = bf2f((unsigned short)(d >> 16));
    }
    __syncthreads();

    // ---- edge phase ----
    const unsigned int* mybuf = bbuf + (size_t)b * cap;
    int nst = (cnt + 63) >> 6;
    for (int s = wave; s < nst; s += 8) {
        int base = s << 6;
        int ei = base + l; if (ei >= cnt) ei = cnt - 1;
        unsigned vpr = mybuf[ei];
        if (base + 64 <= cnt) {                      // full stripe, no masks
#pragma unroll
            for (int sub = 0; sub < 4; sub++) {
                unsigned d_[16]; int dl_[16];
#pragma unroll
                for (int k = 0; k < 16; k++) {
                    unsigned pr = (unsigned)__builtin_amdgcn_readlane((int)vpr, sub * 16 + k);
                    dl_[k] = (int)(pr >> 24);
                    d_[k] = ((const unsigned*)(IN + (size_t)(pr & 0xffffffu) * 128))[l];
                }
#pragma unroll
                for (int k = 0; k < 16; k++) {
                    atomicAdd(&acc[dl_[k] * ACCSTR + off0], bf2f((unsigned short)(d_[k] & 0xffffu)));
                    atomicAdd(&acc[dl_[k] * ACCSTR + off1], bf2f((unsigned short)(d_[k] >> 16)));
                }
            }
        } else {                                     // partial stripe, masked
            int rem = cnt - base;                    // 1..63
#pragma unroll
            for (int sub = 0; sub < 4; sub++) {
                if (sub * 16 >= rem) break;          // uniform
                unsigned d_[16]; int dl_[16]; float mk_[16];
#pragma unroll
                for (int k = 0; k < 16; k++) {
                    unsigned pr = (unsigned)__builtin_amdgcn_readlane((int)vpr, sub * 16 + k);
                    dl_[k] = (int)(pr >> 24);
                    mk_[k] = (sub * 16 + k < rem) ? 1.f : 0.f;
                    d_[k] = ((const unsigned*)(IN + (size_t)(pr & 0xffffffu) * 128))[l];
                }
#pragma unroll
                for (int k = 0; k < 16; k++) {
                    atomicAdd(&acc[dl_[k] * ACCSTR + off0], mk_[k] * bf2f((unsigned short)(d_[k] & 0xffffu)));
                    atomicAdd(&acc[dl_[k] * ACCSTR + off1], mk_[k] * bf2f((unsigned short)(d_[k] >> 16)));
                }
            }
        }
    }
    __syncthreads();

    // ---- epilogue (8 rows per wave) ----
    float2 bb = {0.f, 0.f};
    if (MODE == 1) bb = *(const float2*)(bias + 2 * l);
#pragma unroll
    for (int q = 0; q < 8; q++) {
        int lr = wave * 8 + q;
        int gr = r0 + lr;
        if (gr >= N) break;
        float f0 = acc[lr * ACCSTR + off0];
        float f1 = acc[lr * ACCSTR + off1];
        float dv = dinv[gr];
        if (MODE == 0) {
            unsigned o = ((unsigned)f2bf(f1 * dv) << 16) | (unsigned)f2bf(f0 * dv);
            ((unsigned*)(OP + (size_t)gr * 128))[l] = o;
        } else {
            float2 o;
            o.x = fmaxf(f0 * dv + bb.x, 0.f);
            o.y = fmaxf(f1 * dv + bb.y, 0.f);
            ((float2*)(OF + (size_t)gr * 128))[l] = o;
        }
    }
}

// ---------- MLP: Ts = bf16( (dinv*relu(Xa@W1+b1)) @ W2 ), in-place on P ----------
// Per 16-row tile, 4 waves. All a-frag READS of the tile complete before the
// barrier; Ts WRITES after -> in-place safe (tiles partition rows).
__global__ __launch_bounds__(256, 8) void mlp_kernel(
    const unsigned short* __restrict__ P,
    const unsigned short* __restrict__ W1s, const unsigned short* __restrict__ W2s,
    const float* __restrict__ bias, const float* __restrict__ dinv,
    unsigned short* __restrict__ T, int M) {
    __shared__ unsigned short Ht[16 * LDSTRIDE];
    int t = threadIdx.x, m0 = blockIdx.x * 16;
    int wave = t >> 6, lane = t & 63;
    int mrow = lane & 15, quad = lane >> 4;
    int rr = m0 + mrow; if (rr >= M) rr = M - 1;

    bf16x8 a[4];
#pragma unroll
    for (int kc = 0; kc < 4; kc++)
        a[kc] = *(const bf16x8*)(P + (size_t)rr * 128 + kc * 32 + quad * 8);

    float dv[4];
#pragma unroll
    for (int i2 = 0; i2 < 4; i2++) {
        int gr = m0 + quad * 4 + i2;
        dv[i2] = dinv[gr < M ? gr : M - 1];
    }

    const bf16x8* w1v = (const bf16x8*)W1s;
    for (int nt = wave * 4; nt < wave * 4 + 4; nt++) {
        f32x4 c = {0.f, 0.f, 0.f, 0.f};
#pragma unroll
        for (int kc = 0; kc < 4; kc++) {
            bf16x8 bfr = w1v[(nt * 4 + kc) * 64 + lane];
            c = __builtin_amdgcn_mfma_f32_16x16x32_bf16(a[kc], bfr, c, 0, 0, 0);
        }
        int colc = nt * 16 + mrow;
        float bbv = bias[colc];
#pragma unroll
        for (int i2 = 0; i2 < 4; i2++) {
            float v = fmaxf(c[i2] + bbv, 0.f) * dv[i2];
            Ht[(quad * 4 + i2) * LDSTRIDE + colc] = f2bf(v);
        }
    }
    __syncthreads();

    bf16x8 hh[8];
    const unsigned short* hrow = Ht + mrow * LDSTRIDE + quad * 8;
#pragma unroll
    for (int kc = 0; kc < 8; kc++) hh[kc] = *(const bf16x8*)(hrow + kc * 32);
    const bf16x8* w2v = (const bf16x8*)W2s;
    for (int nt = wave * 2; nt < wave * 2 + 2; nt++) {
        f32x4 c = {0.f, 0.f, 0.f, 0.f};
#pragma unroll
        for (int kc = 0; kc < 8; kc++) {
            bf16x8 bfr = w2v[(nt * 8 + kc) * 64 + lane];
            c = __builtin_amdgcn_mfma_f32_16x16x32_bf16(hh[kc], bfr, c, 0, 0, 0);
        }
        int colc = nt * 16 + mrow;
#pragma unroll
        for (int i2 = 0; i2 < 4; i2++) {
            int gr = m0 + quad * 4 + i2;
            if (gr < M) T[(size_t)gr * 128 + colc] = f2bf(c[i2]);
        }
    }
}

extern "C" void kernel_launch(void* const* d_in, const int* in_sizes, int n_in,
                              void* d_out, int out_size, void* d_ws, size_t ws_size,
                              hipStream_t stream) {
    const float* x  = (const float*)d_in[0];
    const int* ei   = (const int*)d_in[1];     // int32 (JAX x64 disabled)
    const float* W1 = (const float*)d_in[2];
    const float* b1 = (const float*)d_in[3];
    const float* W2 = (const float*)d_in[4];
    const float* b2 = (const float*)d_in[5];
    float* out      = (float*)d_out;

    const int N = in_sizes[0] / 128;
    const int E = in_sizes[1] / 2;
    const int* src = ei;
    const int* dst = ei + E;

    const int nbuck = (N + BMASK) >> BSHIFT;                // 782
    const int cap = E / nbuck + E / (4 * nbuck) + 512;      // ~1790

    // Workspace: dinv | P (Xa then Ts, in-place) | Xs | W1s | W2s | ctrl | bbuf
    float* ws = (float*)d_ws;
    size_t Np = ((size_t)N + 255) & ~(size_t)255;
    float*          dinv = ws;
    unsigned short* P    = (unsigned short*)(dinv + Np);    // N*128 bf16
    unsigned short* Xs   = P + (size_t)N * 128;             // N*128 bf16
    unsigned short* W1s  = Xs + (size_t)N * 128;            // 32768
    unsigned short* W2s  = W1s + 32768;                     // 32768
    int* ctrl = (int*)(W2s + 32768);                        // bcur[1024]
    int* bcur = ctrl;
    unsigned int* bbuf = (unsigned int*)(ctrl + 1024);      // nbuck*cap packed

    // 1. weight swizzle + ctrl zero, then binning + prep
    wswz_kernel<<<256, 256, 0, stream>>>(W1, W2, W1s, W2s, ctrl);
    int nbins = (E + 2047) / 2048;                          // 391
    bin_kernel<<<nbins, 256, 0, stream>>>(src, dst, bcur, bbuf, E, cap, nbuck);
    prep_kernel<<<nbuck, 256, 0, stream>>>(bcur, bbuf, x, dinv, Xs, N, cap);

    // 2. layer-1 scatter aggregate: P = bf16( dinv * (A+I) Xs )
    scat_kernel<0><<<nbuck, 512, 0, stream>>>(bcur, bbuf, Xs, dinv, nullptr,
                                              P, nullptr, N, cap);
    // 3. MLP (GEMM1+GEMM2), in-place P -> Ts
    int mtiles = (N + 15) / 16;
    mlp_kernel<<<mtiles, 256, 0, stream>>>(P, W1s, W2s, b1, dinv, P, N);

    // 4. layer-2 scatter aggregate + bias/relu -> out
    scat_kernel<1><<<nbuck, 512, 0, stream>>>(bcur, bbuf, P, dinv, b2,
                                              nullptr, out, N, cap);
}

// Round 9
// 276.345 us; speedup vs baseline: 5.4511x; 5.4511x over previous
//
#include <hip/hip_runtime.h>

// GCN 2-layer, R22 = R21 + deterministic per-row col sort in bucket_csr.
// R21 post-mortem: kernel CORRECT single-shot (absmax 1.95e-3) but failed the
// replay-repeatability tripwire (2.7e-2): atomic binning makes per-row edge
// order nondeterministic -> f32 sum order varies -> bf16 rounding flips ->
// amplified via layer 2. Fix: insertion-sort each row's col segment (one
// row per thread, ~16 elems) -> bit-identical sums every launch.
// Depth-16 gather batches retained (R20 hypothesis, still unverdicted):
// R18 measured 36 CU-cy/edge = one ~300cy round trip per 8-batch exposed.
//   wswz(+ctrl zero) | bin | bucket_csr(sort,dinv,Xs) | gemm_fused | gather2
// Lessons: no global atomic work queues (R7); no serial stragglers (R9); zero
// ALL control memory (R11); min-waves must fit live regs (R14); don't hand-
// pipeline scattered loads (R16); restructure for fat per-instr rows (R17);
// no serial dependent-load tails (R18); scatter-push dies register-starved
// (R19); ANY atomic-ordered intermediate feeding a float sum must be
// canonicalized (sorted) or the replay tripwire eventually fires (R21).

typedef short bf16x8 __attribute__((ext_vector_type(8)));
typedef float f32x4 __attribute__((ext_vector_type(4)));

#define LDSTRIDE 264   // H tile: 16 rows * 264 ushort = 528 B/row, 16B-aligned
#define XTSTRIDE 136   // A tile: 16 rows * 136 ushort = 272 B/row, 16B-aligned
#define BSHIFT 7       // 128 dsts per bucket
#define BMASK 127

__device__ inline unsigned short f2bf(float f) {          // RNE
    unsigned int u = __float_as_uint(f);
    u += 0x7FFF + ((u >> 16) & 1);
    return (unsigned short)(u >> 16);
}
__device__ inline float bf2f(unsigned short h) {
    return __uint_as_float(((unsigned int)h) << 16);
}

// ---------- W swizzle into MFMA b-frag order + ctrl zero ----------
__device__ inline void swz1(const float* W, unsigned short* Ws, int K, int N, int i) {
    int k = i / N, n = i % N;
    int KC = K >> 5;
    size_t d = ((((size_t)(n >> 4) * KC + (k >> 5)) * 64) + ((k >> 3) & 3) * 16 + (n & 15)) * 8
               + (k & 7);
    Ws[d] = f2bf(W[i]);
}
__global__ void wswz_kernel(const float* __restrict__ W1, const float* __restrict__ W2,
                            unsigned short* __restrict__ W1s, unsigned short* __restrict__ W2s,
                            int* __restrict__ ctrl) {
    int i = blockIdx.x * blockDim.x + threadIdx.x;
    if (blockIdx.x == 0) {                     // zero ALL 512 ctrl ints
        for (int j = threadIdx.x; j < 512; j += 256) ctrl[j] = 0;
    }
    if (i < 32768) swz1(W1, W1s, 128, 256, i);
    else if (i < 65536) swz1(W2, W2s, 256, 128, i - 32768);
}

// ---------- pass 1: bin edges by dst>>7 (4 B packed) ----------
__global__ __launch_bounds__(256) void bin_kernel(
    const int* __restrict__ src, const int* __restrict__ dst,
    int* __restrict__ bcur, unsigned int* __restrict__ bbuf,
    int E, int cap, int nbuck) {
    __shared__ int cnt[512];
    __shared__ int base[512];
    int t = threadIdx.x;
    for (int i = t; i < nbuck; i += 256) cnt[i] = 0;
    __syncthreads();
    int e0 = blockIdx.x * 2048;
    unsigned int p_[8];
    int b_[8];
#pragma unroll
    for (int i = 0; i < 8; i++) {
        int e = e0 + i * 256 + t;
        if (e < E) {
            int s = src[e], d = dst[e];
            b_[i] = d >> BSHIFT;
            p_[i] = ((unsigned)(d & BMASK) << 24) | (unsigned)s;   // N < 2^24
            atomicAdd(&cnt[b_[i]], 1);
        } else b_[i] = -1;
    }
    __syncthreads();
    for (int b = t; b < nbuck; b += 256) {
        int c = cnt[b];
        base[b] = (c > 0) ? atomicAdd(&bcur[b], c) : 0;
    }
    __syncthreads();
    for (int i = t; i < nbuck; i += 256) cnt[i] = 0;   // reuse as cursor
    __syncthreads();
#pragma unroll
    for (int i = 0; i < 8; i++) {
        if (b_[i] >= 0) {
            int b = b_[i];
            int p = base[b] + atomicAdd(&cnt[b], 1);
            if (p >= 0 && p < cap) bbuf[(size_t)b * cap + p] = p_[i];
        }
    }
}

// ---------- pass 2: per-bucket (128 dsts) CSR + row-sort + dinv + Xs ----------
__global__ __launch_bounds__(256) void bucket_csr_kernel(
    const int* __restrict__ bcur, const unsigned int* __restrict__ bbuf,
    const float* __restrict__ x,
    int* __restrict__ col, int* __restrict__ rowbeg, int* __restrict__ rowend,
    float* __restrict__ dinv, unsigned short* __restrict__ Xs, int N, int cap) {
    __shared__ int ldeg[128];
    __shared__ int lrp[256];
    __shared__ float sdv[128];
    int b = blockIdx.x, t = threadIdx.x;
    int cnt = min(max(bcur[b], 0), cap);
    if (t < 128) ldeg[t] = 0;
    __syncthreads();
    const unsigned int* mybuf = bbuf + (size_t)b * cap;
    for (int i = t; i < cnt; i += 256)
        atomicAdd(&ldeg[mybuf[i] >> 24], 1);
    __syncthreads();
    int v = (t < 128) ? ldeg[t] : 0;
    lrp[t] = v;
    __syncthreads();
    for (int off = 1; off < 128; off <<= 1) {    // inclusive scan (128 live)
        int u = (t >= off) ? lrp[t - off] : 0;
        __syncthreads();
        lrp[t] += u;
        __syncthreads();
    }
    int excl = lrp[t] - v;
    int gbase = b * cap;
    if (t < 128) {
        int r = b * 128 + t;
        float dv = rsqrtf((float)v + 1.0f);      // self-loop adds 1
        sdv[t] = dv;
        if (r < N) {
            rowbeg[r] = gbase + excl;
            rowend[r] = gbase + excl + v;
            dinv[r] = dv;
        }
        ldeg[t] = excl;    // reuse as cursor
    }
    __syncthreads();
    for (int i = t; i < cnt; i += 256) {
        unsigned int pr = mybuf[i];
        int p = atomicAdd(&ldeg[pr >> 24], 1);
        col[gbase + p] = (int)(pr & 0xffffffu);
    }
    __syncthreads();
    // deterministic order: insertion-sort each row's col segment by src value.
    // Multiset per row is deterministic -> sorted order makes every downstream
    // f32 sum bit-identical across launches (replay tripwire, R21).
    if (t < 128) {
        int s0 = gbase + excl, s1 = gbase + excl + v;
        for (int a = s0 + 1; a < s1; a++) {
            int key = col[a];
            int j = a - 1;
            while (j >= s0 && col[j] > key) { col[j + 1] = col[j]; j--; }
            col[j + 1] = key;
        }
    }
    // fused Xs: rows b*128..+127, coalesced ushort4
    int rbase = b * 128;
    for (int i = t; i < 128 * 32; i += 256) {
        int rl = i >> 5;
        int gr = rbase + rl;
        if (gr >= N) break;
        float s = sdv[rl];
        float4 xv = ((const float4*)x)[(size_t)gr * 32 + (i & 31)];
        ushort4 o;
        o.x = f2bf(xv.x * s); o.y = f2bf(xv.y * s);
        o.z = f2bf(xv.z * s); o.w = f2bf(xv.w * s);
        ((ushort4*)Xs)[(size_t)gr * 32 + (i & 31)] = o;
    }
}

// 16-deep batched row accumulate: issue 16 independent ushort4 loads, then
// pairwise-tree accumulate. Depth is what hides the ~300cy L3 latency.
#define GLOAD16(Pf, col, i)                                                      \
    ushort4 v0  = *(const ushort4*)((Pf) + (size_t)(col)[(i) + 0]  * 128);       \
    ushort4 v1  = *(const ushort4*)((Pf) + (size_t)(col)[(i) + 1]  * 128);       \
    ushort4 v2  = *(const ushort4*)((Pf) + (size_t)(col)[(i) + 2]  * 128);       \
    ushort4 v3  = *(const ushort4*)((Pf) + (size_t)(col)[(i) + 3]  * 128);       \
    ushort4 v4  = *(const ushort4*)((Pf) + (size_t)(col)[(i) + 4]  * 128);       \
    ushort4 v5  = *(const ushort4*)((Pf) + (size_t)(col)[(i) + 5]  * 128);       \
    ushort4 v6  = *(const ushort4*)((Pf) + (size_t)(col)[(i) + 6]  * 128);       \
    ushort4 v7  = *(const ushort4*)((Pf) + (size_t)(col)[(i) + 7]  * 128);       \
    ushort4 v8  = *(const ushort4*)((Pf) + (size_t)(col)[(i) + 8]  * 128);       \
    ushort4 v9  = *(const ushort4*)((Pf) + (size_t)(col)[(i) + 9]  * 128);       \
    ushort4 v10 = *(const ushort4*)((Pf) + (size_t)(col)[(i) + 10] * 128);       \
    ushort4 v11 = *(const ushort4*)((Pf) + (size_t)(col)[(i) + 11] * 128);       \
    ushort4 v12 = *(const ushort4*)((Pf) + (size_t)(col)[(i) + 12] * 128);       \
    ushort4 v13 = *(const ushort4*)((Pf) + (size_t)(col)[(i) + 13] * 128);       \
    ushort4 v14 = *(const ushort4*)((Pf) + (size_t)(col)[(i) + 14] * 128);       \
    ushort4 v15 = *(const ushort4*)((Pf) + (size_t)(col)[(i) + 15] * 128);       \
    ax += ((bf2f(v0.x) + bf2f(v1.x)) + (bf2f(v2.x) + bf2f(v3.x)))               \
        + ((bf2f(v4.x) + bf2f(v5.x)) + (bf2f(v6.x) + bf2f(v7.x)))               \
        + ((bf2f(v8.x) + bf2f(v9.x)) + (bf2f(v10.x) + bf2f(v11.x)))             \
        + ((bf2f(v12.x) + bf2f(v13.x)) + (bf2f(v14.x) + bf2f(v15.x)));          \
    ay += ((bf2f(v0.y) + bf2f(v1.y)) + (bf2f(v2.y) + bf2f(v3.y)))               \
        + ((bf2f(v4.y) + bf2f(v5.y)) + (bf2f(v6.y) + bf2f(v7.y)))               \
        + ((bf2f(v8.y) + bf2f(v9.y)) + (bf2f(v10.y) + bf2f(v11.y)))             \
        + ((bf2f(v12.y) + bf2f(v13.y)) + (bf2f(v14.y) + bf2f(v15.y)));          \
    az += ((bf2f(v0.z) + bf2f(v1.z)) + (bf2f(v2.z) + bf2f(v3.z)))               \
        + ((bf2f(v4.z) + bf2f(v5.z)) + (bf2f(v6.z) + bf2f(v7.z)))               \
        + ((bf2f(v8.z) + bf2f(v9.z)) + (bf2f(v10.z) + bf2f(v11.z)))             \
        + ((bf2f(v12.z) + bf2f(v13.z)) + (bf2f(v14.z) + bf2f(v15.z)));          \
    aw += ((bf2f(v0.w) + bf2f(v1.w)) + (bf2f(v2.w) + bf2f(v3.w)))               \
        + ((bf2f(v4.w) + bf2f(v5.w)) + (bf2f(v6.w) + bf2f(v7.w)))               \
        + ((bf2f(v8.w) + bf2f(v9.w)) + (bf2f(v10.w) + bf2f(v11.w)))             \
        + ((bf2f(v12.w) + bf2f(v13.w)) + (bf2f(v14.w) + bf2f(v15.w)));

// Masked 8-batch tail: clamped idx + 0/1 selector, no serial dependent chain.
#define GTAIL8(Pf, col, i, end)                                                  \
    if ((i) < (end)) {                                                           \
        int cl = (end) - 1;                                                      \
        int e1 = (i) + 1 < (end) ? (i) + 1 : cl, e2 = (i) + 2 < (end) ? (i) + 2 : cl; \
        int e3 = (i) + 3 < (end) ? (i) + 3 : cl, e4 = (i) + 4 < (end) ? (i) + 4 : cl; \
        int e5 = (i) + 5 < (end) ? (i) + 5 : cl, e6 = (i) + 6 < (end) ? (i) + 6 : cl; \
        int e7 = (i) + 7 < (end) ? (i) + 7 : cl;                                 \
        float m1 = (i) + 1 < (end) ? 1.f : 0.f, m2 = (i) + 2 < (end) ? 1.f : 0.f; \
        float m3 = (i) + 3 < (end) ? 1.f : 0.f, m4 = (i) + 4 < (end) ? 1.f : 0.f; \
        float m5 = (i) + 5 < (end) ? 1.f : 0.f, m6 = (i) + 6 < (end) ? 1.f : 0.f; \
        float m7 = (i) + 7 < (end) ? 1.f : 0.f;                                  \
        ushort4 t0 = *(const ushort4*)((Pf) + (size_t)(col)[(i)] * 128);         \
        ushort4 t1 = *(const ushort4*)((Pf) + (size_t)(col)[e1] * 128);          \
        ushort4 t2 = *(const ushort4*)((Pf) + (size_t)(col)[e2] * 128);          \
        ushort4 t3 = *(const ushort4*)((Pf) + (size_t)(col)[e3] * 128);          \
        ushort4 t4 = *(const ushort4*)((Pf) + (size_t)(col)[e4] * 128);          \
        ushort4 t5 = *(const ushort4*)((Pf) + (size_t)(col)[e5] * 128);          \
        ushort4 t6 = *(const ushort4*)((Pf) + (size_t)(col)[e6] * 128);          \
        ushort4 t7 = *(const ushort4*)((Pf) + (size_t)(col)[e7] * 128);          \
        ax += bf2f(t0.x) + m1 * bf2f(t1.x) + m2 * bf2f(t2.x) + m3 * bf2f(t3.x)  \
            + m4 * bf2f(t4.x) + m5 * bf2f(t5.x) + m6 * bf2f(t6.x) + m7 * bf2f(t7.x); \
        ay += bf2f(t0.y) + m1 * bf2f(t1.y) + m2 * bf2f(t2.y) + m3 * bf2f(t3.y)  \
            + m4 * bf2f(t4.y) + m5 * bf2f(t5.y) + m6 * bf2f(t6.y) + m7 * bf2f(t7.y); \
        az += bf2f(t0.z) + m1 * bf2f(t1.z) + m2 * bf2f(t2.z) + m3 * bf2f(t3.z)  \
            + m4 * bf2f(t4.z) + m5 * bf2f(t5.z) + m6 * bf2f(t6.z) + m7 * bf2f(t7.z); \
        aw += bf2f(t0.w) + m1 * bf2f(t1.w) + m2 * bf2f(t2.w) + m3 * bf2f(t3.w)  \
            + m4 * bf2f(t4.w) + m5 * bf2f(t5.w) + m6 * bf2f(t6.w) + m7 * bf2f(t7.w); \
    }

// ---------- gather2: half-wave per row, 16-deep batches, masked tail ----------
__global__ __launch_bounds__(256, 3) void gather2_kernel(
    const int* __restrict__ rowbeg, const int* __restrict__ rowend,
    const int* __restrict__ col, const unsigned short* __restrict__ P,
    const float* __restrict__ dinv, const float* __restrict__ bias,
    float* __restrict__ OF, int N) {
    int gid = blockIdx.x * blockDim.x + threadIdx.x;
    int r = gid >> 5;
    if (r >= N) return;
    int lane = gid & 31;
    const size_t off = (size_t)lane * 4;
    const unsigned short* Pf = P + off;

    ushort4 u = *(const ushort4*)(Pf + (size_t)r * 128);
    float ax = bf2f(u.x), ay = bf2f(u.y), az = bf2f(u.z), aw = bf2f(u.w);

    int beg = rowbeg[r], end = rowend[r];
    int i = beg;
    for (; i + 15 < end; i += 16) { GLOAD16(Pf, col, i) }
    for (; i + 7 < end; i += 8) {
        ushort4 v0 = *(const ushort4*)(Pf + (size_t)col[i + 0] * 128);
        ushort4 v1 = *(const ushort4*)(Pf + (size_t)col[i + 1] * 128);
        ushort4 v2 = *(const ushort4*)(Pf + (size_t)col[i + 2] * 128);
        ushort4 v3 = *(const ushort4*)(Pf + (size_t)col[i + 3] * 128);
        ushort4 v4 = *(const ushort4*)(Pf + (size_t)col[i + 4] * 128);
        ushort4 v5 = *(const ushort4*)(Pf + (size_t)col[i + 5] * 128);
        ushort4 v6 = *(const ushort4*)(Pf + (size_t)col[i + 6] * 128);
        ushort4 v7 = *(const ushort4*)(Pf + (size_t)col[i + 7] * 128);
        ax += (bf2f(v0.x) + bf2f(v1.x)) + (bf2f(v2.x) + bf2f(v3.x))
            + (bf2f(v4.x) + bf2f(v5.x)) + (bf2f(v6.x) + bf2f(v7.x));
        ay += (bf2f(v0.y) + bf2f(v1.y)) + (bf2f(v2.y) + bf2f(v3.y))
            + (bf2f(v4.y) + bf2f(v5.y)) + (bf2f(v6.y) + bf2f(v7.y));
        az += (bf2f(v0.z) + bf2f(v1.z)) + (bf2f(v2.z) + bf2f(v3.z))
            + (bf2f(v4.z) + bf2f(v5.z)) + (bf2f(v6.z) + bf2f(v7.z));
        aw += (bf2f(v0.w) + bf2f(v1.w)) + (bf2f(v2.w) + bf2f(v3.w))
            + (bf2f(v4.w) + bf2f(v5.w)) + (bf2f(v6.w) + bf2f(v7.w));
    }
    GTAIL8(Pf, col, i, end)
    float s = dinv[r];
    float4 bb = *(const float4*)(bias + off);
    float4 o;
    o.x = fmaxf(ax * s + bb.x, 0.f);
    o.y = fmaxf(ay * s + bb.y, 0.f);
    o.z = fmaxf(az * s + bb.z, 0.f);
    o.w = fmaxf(aw * s + bb.w, 0.f);
    *(float4*)(OF + (size_t)r * 128 + off) = o;
}

// ---------- fused gather1 + GEMM1 + GEMM2, 1 half-wave per row, 16-deep ----------
__global__ __launch_bounds__(512, 3) void gemm_fused_kernel(
    const int* __restrict__ rowbeg, const int* __restrict__ rowend,
    const int* __restrict__ col, const unsigned short* __restrict__ Xs,
    const unsigned short* __restrict__ W1s, const unsigned short* __restrict__ W2s,
    const float* __restrict__ bias, const float* __restrict__ dinv,
    unsigned short* __restrict__ T, int M) {
    __shared__ unsigned short Xt[16 * XTSTRIDE];   // 4352 B: aggregated bf16 A tile
    __shared__ unsigned short Ht[16 * LDSTRIDE];   // 8448 B: H tile

    int t = threadIdx.x;
    int m0 = blockIdx.x * 16;
    int hw = t >> 5;            // half-wave 0..15 = local row
    int l  = t & 31;
    const unsigned short* Pf = Xs + (size_t)l * 4;

    {
        int r = m0 + hw;
        int rc = (r < M) ? r : (M - 1);
        ushort4 u = *(const ushort4*)(Pf + (size_t)rc * 128);   // self-loop
        float ax = bf2f(u.x), ay = bf2f(u.y), az = bf2f(u.z), aw = bf2f(u.w);
        int beg = rowbeg[rc], end = rowend[rc];
        int i = beg;
        for (; i + 15 < end; i += 16) { GLOAD16(Pf, col, i) }
        for (; i + 7 < end; i += 8) {
            ushort4 v0 = *(const ushort4*)(Pf + (size_t)col[i + 0] * 128);
            ushort4 v1 = *(const ushort4*)(Pf + (size_t)col[i + 1] * 128);
            ushort4 v2 = *(const ushort4*)(Pf + (size_t)col[i + 2] * 128);
            ushort4 v3 = *(const ushort4*)(Pf + (size_t)col[i + 3] * 128);
            ushort4 v4 = *(const ushort4*)(Pf + (size_t)col[i + 4] * 128);
            ushort4 v5 = *(const ushort4*)(Pf + (size_t)col[i + 5] * 128);
            ushort4 v6 = *(const ushort4*)(Pf + (size_t)col[i + 6] * 128);
            ushort4 v7 = *(const ushort4*)(Pf + (size_t)col[i + 7] * 128);
            ax += (bf2f(v0.x) + bf2f(v1.x)) + (bf2f(v2.x) + bf2f(v3.x))
                + (bf2f(v4.x) + bf2f(v5.x)) + (bf2f(v6.x) + bf2f(v7.x));
            ay += (bf2f(v0.y) + bf2f(v1.y)) + (bf2f(v2.y) + bf2f(v3.y))
                + (bf2f(v4.y) + bf2f(v5.y)) + (bf2f(v6.y) + bf2f(v7.y));
            az += (bf2f(v0.z) + bf2f(v1.z)) + (bf2f(v2.z) + bf2f(v3.z))
                + (bf2f(v4.z) + bf2f(v5.z)) + (bf2f(v6.z) + bf2f(v7.z));
            aw += (bf2f(v0.w) + bf2f(v1.w)) + (bf2f(v2.w) + bf2f(v3.w))
                + (bf2f(v4.w) + bf2f(v5.w)) + (bf2f(v6.w) + bf2f(v7.w));
        }
        GTAIL8(Pf, col, i, end)
        float dvr = dinv[rc];
        ushort4 o;
        o.x = f2bf(ax * dvr); o.y = f2bf(ay * dvr);
        o.z = f2bf(az * dvr); o.w = f2bf(aw * dvr);
        *(ushort4*)(Xt + hw * XTSTRIDE + l * 4) = o;
    }
    __syncthreads();

    int wave = t >> 6;          // 0..7
    int lane = t & 63;
    int mrow = lane & 15, quad = lane >> 4;

    bf16x8 a[4];
#pragma unroll
    for (int kc = 0; kc < 4; kc++)
        a[kc] = *(const bf16x8*)(Xt + mrow * XTSTRIDE + kc * 32 + quad * 8);

    float dv[4];
#pragma unroll
    for (int i2 = 0; i2 < 4; i2++) {
        int gr = m0 + quad * 4 + i2;
        dv[i2] = dinv[gr < M ? gr : M - 1];
    }

    // ---- GEMM1: 16 nt tiles split 2 per wave -> Ht ----
    const bf16x8* w1v = (const bf16x8*)W1s;
    for (int nt = wave * 2; nt < wave * 2 + 2; nt++) {
        f32x4 c = {0.f, 0.f, 0.f, 0.f};
#pragma unroll
        for (int kc = 0; kc < 4; kc++) {
            bf16x8 b = w1v[(nt * 4 + kc) * 64 + lane];
            c = __builtin_amdgcn_mfma_f32_16x16x32_bf16(a[kc], b, c, 0, 0, 0);
        }
        int colc = nt * 16 + mrow;
        float bb = bias[colc];
#pragma unroll
        for (int i2 = 0; i2 < 4; i2++) {
            float v = fmaxf(c[i2] + bb, 0.f) * dv[i2];
            Ht[(quad * 4 + i2) * LDSTRIDE + colc] = f2bf(v);
        }
    }
    __syncthreads();

    // ---- GEMM2: 8 nt tiles, 1 per wave -> T ----
    bf16x8 hh[8];
    const unsigned short* hrow = Ht + mrow * LDSTRIDE + quad * 8;
#pragma unroll
    for (int kc = 0; kc < 8; kc++) hh[kc] = *(const bf16x8*)(hrow + kc * 32);
    const bf16x8* w2v = (const bf16x8*)W2s;
    {
        int nt = wave;
        f32x4 c = {0.f, 0.f, 0.f, 0.f};
#pragma unroll
        for (int kc = 0; kc < 8; kc++) {
            bf16x8 b = w2v[(nt * 8 + kc) * 64 + lane];
            c = __builtin_amdgcn_mfma_f32_16x16x32_bf16(hh[kc], b, c, 0, 0, 0);
        }
        int colc = nt * 16 + mrow;
#pragma unroll
        for (int i2 = 0; i2 < 4; i2++) {
            int gr = m0 + quad * 4 + i2;
            if (gr < M) T[(size_t)gr * 128 + colc] = f2bf(c[i2]);
        }
    }
}

extern "C" void kernel_launch(void* const* d_in, const int* in_sizes, int n_in,
                              void* d_out, int out_size, void* d_ws, size_t ws_size,
                              hipStream_t stream) {
    const float* x  = (const float*)d_in[0];
    const int* ei   = (const int*)d_in[1];     // int32 (JAX x64 disabled)
    const float* W1 = (const float*)d_in[2];
    const float* b1 = (const float*)d_in[3];
    const float* W2 = (const float*)d_in[4];
    const float* b2 = (const float*)d_in[5];
    float* out      = (float*)d_out;

    const int N = in_sizes[0] / 128;
    const int E = in_sizes[1] / 2;
    const int* src = ei;
    const int* dst = ei + E;

    const int nbuck = (N + BMASK) >> BSHIFT;                // 391
    const int cap = E / nbuck + E / (4 * nbuck) + 512;      // ~3069

    // Workspace: dinv | Ts | Xs | W1s | W2s | rowbeg | rowend | ctrl | bbuf | col
    float* ws = (float*)d_ws;
    size_t Np = ((size_t)N + 255) & ~(size_t)255;
    float*          dinv = ws;
    unsigned short* Ts   = (unsigned short*)(dinv + Np);    // N*128 bf16
    unsigned short* Xs   = Ts + (size_t)N * 128;            // N*128 bf16
    unsigned short* W1s  = Xs + (size_t)N * 128;            // 32768
    unsigned short* W2s  = W1s + 32768;                     // 32768
    int* rowbeg = (int*)(W2s + 32768);                      // N
    int* rowend = rowbeg + Np;                              // N
    int* ctrl   = rowend + Np;                              // bcur[512]
    int* bcur   = ctrl;
    unsigned int* bbuf = (unsigned int*)(ctrl + 512);       // nbuck*cap packed
    int* col    = (int*)(bbuf + (size_t)nbuck * cap);       // nbuck*cap

    // 1. weight swizzle + ctrl zero, then CSR build (+ deterministic row sort)
    wswz_kernel<<<256, 256, 0, stream>>>(W1, W2, W1s, W2s, ctrl);
    int nbins = (E + 2047) / 2048;                          // 391
    bin_kernel<<<nbins, 256, 0, stream>>>(src, dst, bcur, bbuf, E, cap, nbuck);
    bucket_csr_kernel<<<nbuck, 256, 0, stream>>>(bcur, bbuf, x, col, rowbeg, rowend,
                                                 dinv, Xs, N, cap);

    // 2. fused gather1 + GEMM1 + GEMM2 -> Ts (8 waves per 16-row tile)
    int mtiles = (N + 15) / 16;
    gemm_fused_kernel<<<mtiles, 512, 0, stream>>>(rowbeg, rowend, col, Xs,
                                                  W1s, W2s, b1, dinv, Ts, N);

    // 3. gather2 + fused bias/relu -> out
    int gth = N * 32;
    gather2_kernel<<<(gth + 255) / 256, 256, 0, stream>>>(rowbeg, rowend, col, Ts,
                                                          dinv, b2, out, N);
}

// Round 10
// 234.804 us; speedup vs baseline: 6.4155x; 1.1769x over previous
//
#include <hip/hip_runtime.h>

// GCN 2-layer, R23 = R22 with the deterministic row-sort moved into LDS.
// R22 post-mortem: sort on global col[] = serial dependent ~500cy chain per
// compare -> bucket_csr 110us (VALU 2.9%). Fix: scatter bucket cols to LDS
// sh_col[3072] (12KB), insertion-sort rows in LDS, coalesced write-back.
// Depth-16 gather batches retained (R20 hypothesis, verdict still pending:
// R18 measured 36 CU-cy/edge = one ~300cy round trip per 8-batch exposed).
//   wswz(+ctrl zero) | bin | bucket_csr(LDS sort,dinv,Xs) | gemm_fused | gather2
// Lessons: no global atomic work queues (R7); no serial stragglers (R9); zero
// ALL control memory (R11); min-waves must fit live regs (R14); don't hand-
// pipeline scattered loads (R16); restructure for fat per-instr rows (R17);
// no serial dependent-load tails (R18); scatter-push dies register-starved
// (R19); atomic-ordered intermediates feeding float sums must be canonicalized
// (R21); canonicalization must run in LDS, never as global-memory serial
// chains (R22).

typedef short bf16x8 __attribute__((ext_vector_type(8)));
typedef float f32x4 __attribute__((ext_vector_type(4)));

#define LDSTRIDE 264   // H tile: 16 rows * 264 ushort = 528 B/row, 16B-aligned
#define XTSTRIDE 136   // A tile: 16 rows * 136 ushort = 272 B/row, 16B-aligned
#define BSHIFT 7       // 128 dsts per bucket
#define BMASK 127
#define CAPMAX 3072    // sh_col capacity (ints); host cap must be <= this

__device__ inline unsigned short f2bf(float f) {          // RNE
    unsigned int u = __float_as_uint(f);
    u += 0x7FFF + ((u >> 16) & 1);
    return (unsigned short)(u >> 16);
}
__device__ inline float bf2f(unsigned short h) {
    return __uint_as_float(((unsigned int)h) << 16);
}

// ---------- W swizzle into MFMA b-frag order + ctrl zero ----------
__device__ inline void swz1(const float* W, unsigned short* Ws, int K, int N, int i) {
    int k = i / N, n = i % N;
    int KC = K >> 5;
    size_t d = ((((size_t)(n >> 4) * KC + (k >> 5)) * 64) + ((k >> 3) & 3) * 16 + (n & 15)) * 8
               + (k & 7);
    Ws[d] = f2bf(W[i]);
}
__global__ void wswz_kernel(const float* __restrict__ W1, const float* __restrict__ W2,
                            unsigned short* __restrict__ W1s, unsigned short* __restrict__ W2s,
                            int* __restrict__ ctrl) {
    int i = blockIdx.x * blockDim.x + threadIdx.x;
    if (blockIdx.x == 0) {                     // zero ALL 512 ctrl ints
        for (int j = threadIdx.x; j < 512; j += 256) ctrl[j] = 0;
    }
    if (i < 32768) swz1(W1, W1s, 128, 256, i);
    else if (i < 65536) swz1(W2, W2s, 256, 128, i - 32768);
}

// ---------- pass 1: bin edges by dst>>7 (4 B packed) ----------
__global__ __launch_bounds__(256) void bin_kernel(
    const int* __restrict__ src, const int* __restrict__ dst,
    int* __restrict__ bcur, unsigned int* __restrict__ bbuf,
    int E, int cap, int nbuck) {
    __shared__ int cnt[512];
    __shared__ int base[512];
    int t = threadIdx.x;
    for (int i = t; i < nbuck; i += 256) cnt[i] = 0;
    __syncthreads();
    int e0 = blockIdx.x * 2048;
    unsigned int p_[8];
    int b_[8];
#pragma unroll
    for (int i = 0; i < 8; i++) {
        int e = e0 + i * 256 + t;
        if (e < E) {
            int s = src[e], d = dst[e];
            b_[i] = d >> BSHIFT;
            p_[i] = ((unsigned)(d & BMASK) << 24) | (unsigned)s;   // N < 2^24
            atomicAdd(&cnt[b_[i]], 1);
        } else b_[i] = -1;
    }
    __syncthreads();
    for (int b = t; b < nbuck; b += 256) {
        int c = cnt[b];
        base[b] = (c > 0) ? atomicAdd(&bcur[b], c) : 0;
    }
    __syncthreads();
    for (int i = t; i < nbuck; i += 256) cnt[i] = 0;   // reuse as cursor
    __syncthreads();
#pragma unroll
    for (int i = 0; i < 8; i++) {
        if (b_[i] >= 0) {
            int b = b_[i];
            int p = base[b] + atomicAdd(&cnt[b], 1);
            if (p >= 0 && p < cap) bbuf[(size_t)b * cap + p] = p_[i];
        }
    }
}

// ---------- pass 2: per-bucket (128 dsts) CSR + LDS row-sort + dinv + Xs ----------
__global__ __launch_bounds__(256) void bucket_csr_kernel(
    const int* __restrict__ bcur, const unsigned int* __restrict__ bbuf,
    const float* __restrict__ x,
    int* __restrict__ col, int* __restrict__ rowbeg, int* __restrict__ rowend,
    float* __restrict__ dinv, unsigned short* __restrict__ Xs, int N, int cap) {
    __shared__ int ldeg[128];
    __shared__ int lrp[256];
    __shared__ float sdv[128];
    __shared__ int sh_col[CAPMAX];               // 12288 B: bucket cols, local idx
    int b = blockIdx.x, t = threadIdx.x;
    int cnt = min(max(bcur[b], 0), cap);
    if (t < 128) ldeg[t] = 0;
    __syncthreads();
    const unsigned int* mybuf = bbuf + (size_t)b * cap;
    for (int i = t; i < cnt; i += 256)
        atomicAdd(&ldeg[mybuf[i] >> 24], 1);
    __syncthreads();
    int v = (t < 128) ? ldeg[t] : 0;
    lrp[t] = v;
    __syncthreads();
    for (int off = 1; off < 128; off <<= 1) {    // inclusive scan (128 live)
        int u = (t >= off) ? lrp[t - off] : 0;
        __syncthreads();
        lrp[t] += u;
        __syncthreads();
    }
    int excl = lrp[t] - v;
    int gbase = b * cap;
    if (t < 128) {
        int r = b * 128 + t;
        float dv = rsqrtf((float)v + 1.0f);      // self-loop adds 1
        sdv[t] = dv;
        if (r < N) {
            rowbeg[r] = gbase + excl;
            rowend[r] = gbase + excl + v;
            dinv[r] = dv;
        }
        ldeg[t] = excl;    // reuse as LOCAL cursor
    }
    __syncthreads();
    for (int i = t; i < cnt; i += 256) {         // scatter into LDS (local pos)
        unsigned int pr = mybuf[i];
        int p = atomicAdd(&ldeg[pr >> 24], 1);
        sh_col[p] = (int)(pr & 0xffffffu);
    }
    __syncthreads();
    // deterministic order: insertion-sort each row's segment IN LDS by src.
    // Multiset per row is deterministic -> sorted order makes every downstream
    // f32 sum bit-identical across launches (replay tripwire, R21). LDS venue
    // (~3cy/op) not global (~500cy/op serial chain, R22's 110us mistake).
    if (t < 128) {
        int s0 = excl, s1 = excl + v;
        for (int a2 = s0 + 1; a2 < s1; a2++) {
            int key = sh_col[a2];
            int j = a2 - 1;
            while (j >= s0 && sh_col[j] > key) { sh_col[j + 1] = sh_col[j]; j--; }
            sh_col[j + 1] = key;
        }
    }
    __syncthreads();
    for (int i = t; i < cnt; i += 256)           // coalesced write-back
        col[gbase + i] = sh_col[i];
    // fused Xs: rows b*128..+127, coalesced ushort4
    int rbase = b * 128;
    for (int i = t; i < 128 * 32; i += 256) {
        int rl = i >> 5;
        int gr = rbase + rl;
        if (gr >= N) break;
        float s = sdv[rl];
        float4 xv = ((const float4*)x)[(size_t)gr * 32 + (i & 31)];
        ushort4 o;
        o.x = f2bf(xv.x * s); o.y = f2bf(xv.y * s);
        o.z = f2bf(xv.z * s); o.w = f2bf(xv.w * s);
        ((ushort4*)Xs)[(size_t)gr * 32 + (i & 31)] = o;
    }
}

// 16-deep batched row accumulate: issue 16 independent ushort4 loads, then
// pairwise-tree accumulate. Depth is what hides the ~300cy L3 latency.
#define GLOAD16(Pf, col, i)                                                      \
    ushort4 v0  = *(const ushort4*)((Pf) + (size_t)(col)[(i) + 0]  * 128);       \
    ushort4 v1  = *(const ushort4*)((Pf) + (size_t)(col)[(i) + 1]  * 128);       \
    ushort4 v2  = *(const ushort4*)((Pf) + (size_t)(col)[(i) + 2]  * 128);       \
    ushort4 v3  = *(const ushort4*)((Pf) + (size_t)(col)[(i) + 3]  * 128);       \
    ushort4 v4  = *(const ushort4*)((Pf) + (size_t)(col)[(i) + 4]  * 128);       \
    ushort4 v5  = *(const ushort4*)((Pf) + (size_t)(col)[(i) + 5]  * 128);       \
    ushort4 v6  = *(const ushort4*)((Pf) + (size_t)(col)[(i) + 6]  * 128);       \
    ushort4 v7  = *(const ushort4*)((Pf) + (size_t)(col)[(i) + 7]  * 128);       \
    ushort4 v8  = *(const ushort4*)((Pf) + (size_t)(col)[(i) + 8]  * 128);       \
    ushort4 v9  = *(const ushort4*)((Pf) + (size_t)(col)[(i) + 9]  * 128);       \
    ushort4 v10 = *(const ushort4*)((Pf) + (size_t)(col)[(i) + 10] * 128);       \
    ushort4 v11 = *(const ushort4*)((Pf) + (size_t)(col)[(i) + 11] * 128);       \
    ushort4 v12 = *(const ushort4*)((Pf) + (size_t)(col)[(i) + 12] * 128);       \
    ushort4 v13 = *(const ushort4*)((Pf) + (size_t)(col)[(i) + 13] * 128);       \
    ushort4 v14 = *(const ushort4*)((Pf) + (size_t)(col)[(i) + 14] * 128);       \
    ushort4 v15 = *(const ushort4*)((Pf) + (size_t)(col)[(i) + 15] * 128);       \
    ax += ((bf2f(v0.x) + bf2f(v1.x)) + (bf2f(v2.x) + bf2f(v3.x)))               \
        + ((bf2f(v4.x) + bf2f(v5.x)) + (bf2f(v6.x) + bf2f(v7.x)))               \
        + ((bf2f(v8.x) + bf2f(v9.x)) + (bf2f(v10.x) + bf2f(v11.x)))             \
        + ((bf2f(v12.x) + bf2f(v13.x)) + (bf2f(v14.x) + bf2f(v15.x)));          \
    ay += ((bf2f(v0.y) + bf2f(v1.y)) + (bf2f(v2.y) + bf2f(v3.y)))               \
        + ((bf2f(v4.y) + bf2f(v5.y)) + (bf2f(v6.y) + bf2f(v7.y)))               \
        + ((bf2f(v8.y) + bf2f(v9.y)) + (bf2f(v10.y) + bf2f(v11.y)))             \
        + ((bf2f(v12.y) + bf2f(v13.y)) + (bf2f(v14.y) + bf2f(v15.y)));          \
    az += ((bf2f(v0.z) + bf2f(v1.z)) + (bf2f(v2.z) + bf2f(v3.z)))               \
        + ((bf2f(v4.z) + bf2f(v5.z)) + (bf2f(v6.z) + bf2f(v7.z)))               \
        + ((bf2f(v8.z) + bf2f(v9.z)) + (bf2f(v10.z) + bf2f(v11.z)))             \
        + ((bf2f(v12.z) + bf2f(v13.z)) + (bf2f(v14.z) + bf2f(v15.z)));          \
    aw += ((bf2f(v0.w) + bf2f(v1.w)) + (bf2f(v2.w) + bf2f(v3.w)))               \
        + ((bf2f(v4.w) + bf2f(v5.w)) + (bf2f(v6.w) + bf2f(v7.w)))               \
        + ((bf2f(v8.w) + bf2f(v9.w)) + (bf2f(v10.w) + bf2f(v11.w)))             \
        + ((bf2f(v12.w) + bf2f(v13.w)) + (bf2f(v14.w) + bf2f(v15.w)));

// Masked 8-batch tail: clamped idx + 0/1 selector, no serial dependent chain.
#define GTAIL8(Pf, col, i, end)                                                  \
    if ((i) < (end)) {                                                           \
        int cl = (end) - 1;                                                      \
        int e1 = (i) + 1 < (end) ? (i) + 1 : cl, e2 = (i) + 2 < (end) ? (i) + 2 : cl; \
        int e3 = (i) + 3 < (end) ? (i) + 3 : cl, e4 = (i) + 4 < (end) ? (i) + 4 : cl; \
        int e5 = (i) + 5 < (end) ? (i) + 5 : cl, e6 = (i) + 6 < (end) ? (i) + 6 : cl; \
        int e7 = (i) + 7 < (end) ? (i) + 7 : cl;                                 \
        float m1 = (i) + 1 < (end) ? 1.f : 0.f, m2 = (i) + 2 < (end) ? 1.f : 0.f; \
        float m3 = (i) + 3 < (end) ? 1.f : 0.f, m4 = (i) + 4 < (end) ? 1.f : 0.f; \
        float m5 = (i) + 5 < (end) ? 1.f : 0.f, m6 = (i) + 6 < (end) ? 1.f : 0.f; \
        float m7 = (i) + 7 < (end) ? 1.f : 0.f;                                  \
        ushort4 t0 = *(const ushort4*)((Pf) + (size_t)(col)[(i)] * 128);         \
        ushort4 t1 = *(const ushort4*)((Pf) + (size_t)(col)[e1] * 128);          \
        ushort4 t2 = *(const ushort4*)((Pf) + (size_t)(col)[e2] * 128);          \
        ushort4 t3 = *(const ushort4*)((Pf) + (size_t)(col)[e3] * 128);          \
        ushort4 t4 = *(const ushort4*)((Pf) + (size_t)(col)[e4] * 128);          \
        ushort4 t5 = *(const ushort4*)((Pf) + (size_t)(col)[e5] * 128);          \
        ushort4 t6 = *(const ushort4*)((Pf) + (size_t)(col)[e6] * 128);          \
        ushort4 t7 = *(const ushort4*)((Pf) + (size_t)(col)[e7] * 128);          \
        ax += bf2f(t0.x) + m1 * bf2f(t1.x) + m2 * bf2f(t2.x) + m3 * bf2f(t3.x)  \
            + m4 * bf2f(t4.x) + m5 * bf2f(t5.x) + m6 * bf2f(t6.x) + m7 * bf2f(t7.x); \
        ay += bf2f(t0.y) + m1 * bf2f(t1.y) + m2 * bf2f(t2.y) + m3 * bf2f(t3.y)  \
            + m4 * bf2f(t4.y) + m5 * bf2f(t5.y) + m6 * bf2f(t6.y) + m7 * bf2f(t7.y); \
        az += bf2f(t0.z) + m1 * bf2f(t1.z) + m2 * bf2f(t2.z) + m3 * bf2f(t3.z)  \
            + m4 * bf2f(t4.z) + m5 * bf2f(t5.z) + m6 * bf2f(t6.z) + m7 * bf2f(t7.z); \
        aw += bf2f(t0.w) + m1 * bf2f(t1.w) + m2 * bf2f(t2.w) + m3 * bf2f(t3.w)  \
            + m4 * bf2f(t4.w) + m5 * bf2f(t5.w) + m6 * bf2f(t6.w) + m7 * bf2f(t7.w); \
    }

// ---------- gather2: half-wave per row, 16-deep batches, masked tail ----------
__global__ __launch_bounds__(256, 3) void gather2_kernel(
    const int* __restrict__ rowbeg, const int* __restrict__ rowend,
    const int* __restrict__ col, const unsigned short* __restrict__ P,
    const float* __restrict__ dinv, const float* __restrict__ bias,
    float* __restrict__ OF, int N) {
    int gid = blockIdx.x * blockDim.x + threadIdx.x;
    int r = gid >> 5;
    if (r >= N) return;
    int lane = gid & 31;
    const size_t off = (size_t)lane * 4;
    const unsigned short* Pf = P + off;

    ushort4 u = *(const ushort4*)(Pf + (size_t)r * 128);
    float ax = bf2f(u.x), ay = bf2f(u.y), az = bf2f(u.z), aw = bf2f(u.w);

    int beg = rowbeg[r], end = rowend[r];
    int i = beg;
    for (; i + 15 < end; i += 16) { GLOAD16(Pf, col, i) }
    for (; i + 7 < end; i += 8) {
        ushort4 v0 = *(const ushort4*)(Pf + (size_t)col[i + 0] * 128);
        ushort4 v1 = *(const ushort4*)(Pf + (size_t)col[i + 1] * 128);
        ushort4 v2 = *(const ushort4*)(Pf + (size_t)col[i + 2] * 128);
        ushort4 v3 = *(const ushort4*)(Pf + (size_t)col[i + 3] * 128);
        ushort4 v4 = *(const ushort4*)(Pf + (size_t)col[i + 4] * 128);
        ushort4 v5 = *(const ushort4*)(Pf + (size_t)col[i + 5] * 128);
        ushort4 v6 = *(const ushort4*)(Pf + (size_t)col[i + 6] * 128);
        ushort4 v7 = *(const ushort4*)(Pf + (size_t)col[i + 7] * 128);
        ax += (bf2f(v0.x) + bf2f(v1.x)) + (bf2f(v2.x) + bf2f(v3.x))
            + (bf2f(v4.x) + bf2f(v5.x)) + (bf2f(v6.x) + bf2f(v7.x));
        ay += (bf2f(v0.y) + bf2f(v1.y)) + (bf2f(v2.y) + bf2f(v3.y))
            + (bf2f(v4.y) + bf2f(v5.y)) + (bf2f(v6.y) + bf2f(v7.y));
        az += (bf2f(v0.z) + bf2f(v1.z)) + (bf2f(v2.z) + bf2f(v3.z))
            + (bf2f(v4.z) + bf2f(v5.z)) + (bf2f(v6.z) + bf2f(v7.z));
        aw += (bf2f(v0.w) + bf2f(v1.w)) + (bf2f(v2.w) + bf2f(v3.w))
            + (bf2f(v4.w) + bf2f(v5.w)) + (bf2f(v6.w) + bf2f(v7.w));
    }
    GTAIL8(Pf, col, i, end)
    float s = dinv[r];
    float4 bb = *(const float4*)(bias + off);
    float4 o;
    o.x = fmaxf(ax * s + bb.x, 0.f);
    o.y = fmaxf(ay * s + bb.y, 0.f);
    o.z = fmaxf(az * s + bb.z, 0.f);
    o.w = fmaxf(aw * s + bb.w, 0.f);
    *(float4*)(OF + (size_t)r * 128 + off) = o;
}

// ---------- fused gather1 + GEMM1 + GEMM2, 1 half-wave per row, 16-deep ----------
__global__ __launch_bounds__(512, 3) void gemm_fused_kernel(
    const int* __restrict__ rowbeg, const int* __restrict__ rowend,
    const int* __restrict__ col, const unsigned short* __restrict__ Xs,
    const unsigned short* __restrict__ W1s, const unsigned short* __restrict__ W2s,
    const float* __restrict__ bias, const float* __restrict__ dinv,
    unsigned short* __restrict__ T, int M) {
    __shared__ unsigned short Xt[16 * XTSTRIDE];   // 4352 B: aggregated bf16 A tile
    __shared__ unsigned short Ht[16 * LDSTRIDE];   // 8448 B: H tile

    int t = threadIdx.x;
    int m0 = blockIdx.x * 16;
    int hw = t >> 5;            // half-wave 0..15 = local row
    int l  = t & 31;
    const unsigned short* Pf = Xs + (size_t)l * 4;

    {
        int r = m0 + hw;
        int rc = (r < M) ? r : (M - 1);
        ushort4 u = *(const ushort4*)(Pf + (size_t)rc * 128);   // self-loop
        float ax = bf2f(u.x), ay = bf2f(u.y), az = bf2f(u.z), aw = bf2f(u.w);
        int beg = rowbeg[rc], end = rowend[rc];
        int i = beg;
        for (; i + 15 < end; i += 16) { GLOAD16(Pf, col, i) }
        for (; i + 7 < end; i += 8) {
            ushort4 v0 = *(const ushort4*)(Pf + (size_t)col[i + 0] * 128);
            ushort4 v1 = *(const ushort4*)(Pf + (size_t)col[i + 1] * 128);
            ushort4 v2 = *(const ushort4*)(Pf + (size_t)col[i + 2] * 128);
            ushort4 v3 = *(const ushort4*)(Pf + (size_t)col[i + 3] * 128);
            ushort4 v4 = *(const ushort4*)(Pf + (size_t)col[i + 4] * 128);
            ushort4 v5 = *(const ushort4*)(Pf + (size_t)col[i + 5] * 128);
            ushort4 v6 = *(const ushort4*)(Pf + (size_t)col[i + 6] * 128);
            ushort4 v7 = *(const ushort4*)(Pf + (size_t)col[i + 7] * 128);
            ax += (bf2f(v0.x) + bf2f(v1.x)) + (bf2f(v2.x) + bf2f(v3.x))
                + (bf2f(v4.x) + bf2f(v5.x)) + (bf2f(v6.x) + bf2f(v7.x));
            ay += (bf2f(v0.y) + bf2f(v1.y)) + (bf2f(v2.y) + bf2f(v3.y))
                + (bf2f(v4.y) + bf2f(v5.y)) + (bf2f(v6.y) + bf2f(v7.y));
            az += (bf2f(v0.z) + bf2f(v1.z)) + (bf2f(v2.z) + bf2f(v3.z))
                + (bf2f(v4.z) + bf2f(v5.z)) + (bf2f(v6.z) + bf2f(v7.z));
            aw += (bf2f(v0.w) + bf2f(v1.w)) + (bf2f(v2.w) + bf2f(v3.w))
                + (bf2f(v4.w) + bf2f(v5.w)) + (bf2f(v6.w) + bf2f(v7.w));
        }
        GTAIL8(Pf, col, i, end)
        float dvr = dinv[rc];
        ushort4 o;
        o.x = f2bf(ax * dvr); o.y = f2bf(ay * dvr);
        o.z = f2bf(az * dvr); o.w = f2bf(aw * dvr);
        *(ushort4*)(Xt + hw * XTSTRIDE + l * 4) = o;
    }
    __syncthreads();

    int wave = t >> 6;          // 0..7
    int lane = t & 63;
    int mrow = lane & 15, quad = lane >> 4;

    bf16x8 a[4];
#pragma unroll
    for (int kc = 0; kc < 4; kc++)
        a[kc] = *(const bf16x8*)(Xt + mrow * XTSTRIDE + kc * 32 + quad * 8);

    float dv[4];
#pragma unroll
    for (int i2 = 0; i2 < 4; i2++) {
        int gr = m0 + quad * 4 + i2;
        dv[i2] = dinv[gr < M ? gr : M - 1];
    }

    // ---- GEMM1: 16 nt tiles split 2 per wave -> Ht ----
    const bf16x8* w1v = (const bf16x8*)W1s;
    for (int nt = wave * 2; nt < wave * 2 + 2; nt++) {
        f32x4 c = {0.f, 0.f, 0.f, 0.f};
#pragma unroll
        for (int kc = 0; kc < 4; kc++) {
            bf16x8 b = w1v[(nt * 4 + kc) * 64 + lane];
            c = __builtin_amdgcn_mfma_f32_16x16x32_bf16(a[kc], b, c, 0, 0, 0);
        }
        int colc = nt * 16 + mrow;
        float bb = bias[colc];
#pragma unroll
        for (int i2 = 0; i2 < 4; i2++) {
            float v = fmaxf(c[i2] + bb, 0.f) * dv[i2];
            Ht[(quad * 4 + i2) * LDSTRIDE + colc] = f2bf(v);
        }
    }
    __syncthreads();

    // ---- GEMM2: 8 nt tiles, 1 per wave -> T ----
    bf16x8 hh[8];
    const unsigned short* hrow = Ht + mrow * LDSTRIDE + quad * 8;
#pragma unroll
    for (int kc = 0; kc < 8; kc++) hh[kc] = *(const bf16x8*)(hrow + kc * 32);
    const bf16x8* w2v = (const bf16x8*)W2s;
    {
        int nt = wave;
        f32x4 c = {0.f, 0.f, 0.f, 0.f};
#pragma unroll
        for (int kc = 0; kc < 8; kc++) {
            bf16x8 b = w2v[(nt * 8 + kc) * 64 + lane];
            c = __builtin_amdgcn_mfma_f32_16x16x32_bf16(hh[kc], b, c, 0, 0, 0);
        }
        int colc = nt * 16 + mrow;
#pragma unroll
        for (int i2 = 0; i2 < 4; i2++) {
            int gr = m0 + quad * 4 + i2;
            if (gr < M) T[(size_t)gr * 128 + colc] = f2bf(c[i2]);
        }
    }
}

extern "C" void kernel_launch(void* const* d_in, const int* in_sizes, int n_in,
                              void* d_out, int out_size, void* d_ws, size_t ws_size,
                              hipStream_t stream) {
    const float* x  = (const float*)d_in[0];
    const int* ei   = (const int*)d_in[1];     // int32 (JAX x64 disabled)
    const float* W1 = (const float*)d_in[2];
    const float* b1 = (const float*)d_in[3];
    const float* W2 = (const float*)d_in[4];
    const float* b2 = (const float*)d_in[5];
    float* out      = (float*)d_out;

    const int N = in_sizes[0] / 128;
    const int E = in_sizes[1] / 2;
    const int* src = ei;
    const int* dst = ei + E;

    const int nbuck = (N + BMASK) >> BSHIFT;                // 391
    int cap = E / nbuck + E / (4 * nbuck) + 512;            // ~3069
    if (cap > CAPMAX) cap = CAPMAX;                         // sh_col bound

    // Workspace: dinv | Ts | Xs | W1s | W2s | rowbeg | rowend | ctrl | bbuf | col
    float* ws = (float*)d_ws;
    size_t Np = ((size_t)N + 255) & ~(size_t)255;
    float*          dinv = ws;
    unsigned short* Ts   = (unsigned short*)(dinv + Np);    // N*128 bf16
    unsigned short* Xs   = Ts + (size_t)N * 128;            // N*128 bf16
    unsigned short* W1s  = Xs + (size_t)N * 128;            // 32768
    unsigned short* W2s  = W1s + 32768;                     // 32768
    int* rowbeg = (int*)(W2s + 32768);                      // N
    int* rowend = rowbeg + Np;                              // N
    int* ctrl   = rowend + Np;                              // bcur[512]
    int* bcur   = ctrl;
    unsigned int* bbuf = (unsigned int*)(ctrl + 512);       // nbuck*cap packed
    int* col    = (int*)(bbuf + (size_t)nbuck * cap);       // nbuck*cap

    // 1. weight swizzle + ctrl zero, then CSR build (+ deterministic LDS sort)
    wswz_kernel<<<256, 256, 0, stream>>>(W1, W2, W1s, W2s, ctrl);
    int nbins = (E + 2047) / 2048;                          // 391
    bin_kernel<<<nbins, 256, 0, stream>>>(src, dst, bcur, bbuf, E, cap, nbuck);
    bucket_csr_kernel<<<nbuck, 256, 0, stream>>>(bcur, bbuf, x, col, rowbeg, rowend,
                                                 dinv, Xs, N, cap);

    // 2. fused gather1 + GEMM1 + GEMM2 -> Ts (8 waves per 16-row tile)
    int mtiles = (N + 15) / 16;
    gemm_fused_kernel<<<mtiles, 512, 0, stream>>>(rowbeg, rowend, col, Xs,
                                                  W1s, W2s, b1, dinv, Ts, N);

    // 3. gather2 + fused bias/relu -> out
    int gth = N * 32;
    gather2_kernel<<<(gth + 255) / 256, 256, 0, stream>>>(rowbeg, rowend, col, Ts,
                                                          dinv, b2, out, N);
}

// Round 11
// 209.543 us; speedup vs baseline: 7.1889x; 1.1206x over previous
//
#include <hip/hip_runtime.h>

// GCN 2-layer, R24 = R23 with the LDS row-sort replaced by a PARALLEL rank
// sort. R23 post-mortem: insertion sort = serial dependent LDS chain per
// thread (O(d^2) round trips, 128/256 threads idle, occ 11%, VALU 5%) ->
// bucket_csr still 59us. Rank sort: each element independently counts
// smaller elements in its row segment (~16 pipelineable LDS reads) and
// writes its slot directly - no dependent chain, all 256 threads active.
// Ties (equal src) produce identical array content -> still deterministic.
// Depth-16 gather batches retained (R20 hypothesis, verdict pending).
//   wswz(+ctrl zero) | bin | bucket_csr(rank-sort,dinv,Xs) | gemm_fused | gather2
// Lessons: no global atomic work queues (R7); no serial stragglers (R9); zero
// ALL control memory (R11); min-waves must fit live regs (R14); don't hand-
// pipeline scattered loads (R16); restructure for fat per-instr rows (R17);
// no serial dependent-load tails (R18); scatter-push dies register-starved
// (R19); atomic-ordered intermediates feeding float sums must be
// canonicalized (R21); canonicalization in LDS (R22) AND with parallel
// rank-sort, never serial per-row loops (R23).

typedef short bf16x8 __attribute__((ext_vector_type(8)));
typedef float f32x4 __attribute__((ext_vector_type(4)));

#define LDSTRIDE 264   // H tile: 16 rows * 264 ushort = 528 B/row, 16B-aligned
#define XTSTRIDE 136   // A tile: 16 rows * 136 ushort = 272 B/row, 16B-aligned
#define BSHIFT 7       // 128 dsts per bucket
#define BMASK 127
#define CAPMAX 3072    // sh_col capacity (ints); host cap must be <= this

__device__ inline unsigned short f2bf(float f) {          // RNE
    unsigned int u = __float_as_uint(f);
    u += 0x7FFF + ((u >> 16) & 1);
    return (unsigned short)(u >> 16);
}
__device__ inline float bf2f(unsigned short h) {
    return __uint_as_float(((unsigned int)h) << 16);
}

// ---------- W swizzle into MFMA b-frag order + ctrl zero ----------
__device__ inline void swz1(const float* W, unsigned short* Ws, int K, int N, int i) {
    int k = i / N, n = i % N;
    int KC = K >> 5;
    size_t d = ((((size_t)(n >> 4) * KC + (k >> 5)) * 64) + ((k >> 3) & 3) * 16 + (n & 15)) * 8
               + (k & 7);
    Ws[d] = f2bf(W[i]);
}
__global__ void wswz_kernel(const float* __restrict__ W1, const float* __restrict__ W2,
                            unsigned short* __restrict__ W1s, unsigned short* __restrict__ W2s,
                            int* __restrict__ ctrl) {
    int i = blockIdx.x * blockDim.x + threadIdx.x;
    if (blockIdx.x == 0) {                     // zero ALL 512 ctrl ints
        for (int j = threadIdx.x; j < 512; j += 256) ctrl[j] = 0;
    }
    if (i < 32768) swz1(W1, W1s, 128, 256, i);
    else if (i < 65536) swz1(W2, W2s, 256, 128, i - 32768);
}

// ---------- pass 1: bin edges by dst>>7 (4 B packed) ----------
__global__ __launch_bounds__(256) void bin_kernel(
    const int* __restrict__ src, const int* __restrict__ dst,
    int* __restrict__ bcur, unsigned int* __restrict__ bbuf,
    int E, int cap, int nbuck) {
    __shared__ int cnt[512];
    __shared__ int base[512];
    int t = threadIdx.x;
    for (int i = t; i < nbuck; i += 256) cnt[i] = 0;
    __syncthreads();
    int e0 = blockIdx.x * 2048;
    unsigned int p_[8];
    int b_[8];
#pragma unroll
    for (int i = 0; i < 8; i++) {
        int e = e0 + i * 256 + t;
        if (e < E) {
            int s = src[e], d = dst[e];
            b_[i] = d >> BSHIFT;
            p_[i] = ((unsigned)(d & BMASK) << 24) | (unsigned)s;   // N < 2^24
            atomicAdd(&cnt[b_[i]], 1);
        } else b_[i] = -1;
    }
    __syncthreads();
    for (int b = t; b < nbuck; b += 256) {
        int c = cnt[b];
        base[b] = (c > 0) ? atomicAdd(&bcur[b], c) : 0;
    }
    __syncthreads();
    for (int i = t; i < nbuck; i += 256) cnt[i] = 0;   // reuse as cursor
    __syncthreads();
#pragma unroll
    for (int i = 0; i < 8; i++) {
        if (b_[i] >= 0) {
            int b = b_[i];
            int p = base[b] + atomicAdd(&cnt[b], 1);
            if (p >= 0 && p < cap) bbuf[(size_t)b * cap + p] = p_[i];
        }
    }
}

// ---------- pass 2: per-bucket (128 dsts) CSR + parallel rank sort + Xs ----------
__global__ __launch_bounds__(256) void bucket_csr_kernel(
    const int* __restrict__ bcur, const unsigned int* __restrict__ bbuf,
    const float* __restrict__ x,
    int* __restrict__ col, int* __restrict__ rowbeg, int* __restrict__ rowend,
    float* __restrict__ dinv, unsigned short* __restrict__ Xs, int N, int cap) {
    __shared__ int ldeg[128];
    __shared__ int sbeg[128];
    __shared__ int lrp[256];
    __shared__ float sdv[128];
    __shared__ int sh_col[CAPMAX];               // 12288 B: packed (row<<24)|src
    int b = blockIdx.x, t = threadIdx.x;
    int cnt = min(max(bcur[b], 0), cap);
    if (t < 128) ldeg[t] = 0;
    __syncthreads();
    const unsigned int* mybuf = bbuf + (size_t)b * cap;
    for (int i = t; i < cnt; i += 256)
        atomicAdd(&ldeg[mybuf[i] >> 24], 1);
    __syncthreads();
    int v = (t < 128) ? ldeg[t] : 0;
    lrp[t] = v;
    __syncthreads();
    for (int off = 1; off < 128; off <<= 1) {    // inclusive scan (128 live)
        int u = (t >= off) ? lrp[t - off] : 0;
        __syncthreads();
        lrp[t] += u;
        __syncthreads();
    }
    int excl = lrp[t] - v;
    int gbase = b * cap;
    if (t < 128) {
        int r = b * 128 + t;
        float dv = rsqrtf((float)v + 1.0f);      // self-loop adds 1
        sdv[t] = dv;
        if (r < N) {
            rowbeg[r] = gbase + excl;
            rowend[r] = gbase + excl + v;
            dinv[r] = dv;
        }
        sbeg[t] = excl;    // segment start (stable)
        ldeg[t] = excl;    // LOCAL scatter cursor
    }
    __syncthreads();
    for (int i = t; i < cnt; i += 256) {         // scatter packed vals into LDS
        unsigned int pr = mybuf[i];
        int p = atomicAdd(&ldeg[pr >> 24], 1);
        sh_col[p] = (int)pr;                     // keep row bits for compare
    }
    __syncthreads();
    // deterministic order via PARALLEL rank sort: element i's slot =
    // segment_start + #{j: v_j < v_i} + #{j: v_j == v_i && j < i}. Equal
    // values are interchangeable -> array content is launch-invariant even
    // though the tie index order is not. ~deg independent LDS reads per
    // element, no dependent chain (R23's serial insertion sort mistake).
    for (int i = t; i < cnt; i += 256) {
        int vi = sh_col[i];
        int row = ((unsigned)vi) >> 24;
        int s0 = sbeg[row];
        int s1 = ldeg[row];                      // = s0 + deg (post-scatter)
        int rank = 0;
        for (int j = s0; j < s1; j++) {
            int vj = sh_col[j];
            rank += (vj < vi || (vj == vi && j < i)) ? 1 : 0;
        }
        col[gbase + s0 + rank] = vi & 0xffffff;
    }
    // fused Xs: rows b*128..+127, coalesced ushort4
    int rbase = b * 128;
    for (int i = t; i < 128 * 32; i += 256) {
        int rl = i >> 5;
        int gr = rbase + rl;
        if (gr >= N) break;
        float s = sdv[rl];
        float4 xv = ((const float4*)x)[(size_t)gr * 32 + (i & 31)];
        ushort4 o;
        o.x = f2bf(xv.x * s); o.y = f2bf(xv.y * s);
        o.z = f2bf(xv.z * s); o.w = f2bf(xv.w * s);
        ((ushort4*)Xs)[(size_t)gr * 32 + (i & 31)] = o;
    }
}

// 16-deep batched row accumulate: issue 16 independent ushort4 loads, then
// pairwise-tree accumulate. Depth is what hides the ~300cy L3 latency.
#define GLOAD16(Pf, col, i)                                                      \
    ushort4 v0  = *(const ushort4*)((Pf) + (size_t)(col)[(i) + 0]  * 128);       \
    ushort4 v1  = *(const ushort4*)((Pf) + (size_t)(col)[(i) + 1]  * 128);       \
    ushort4 v2  = *(const ushort4*)((Pf) + (size_t)(col)[(i) + 2]  * 128);       \
    ushort4 v3  = *(const ushort4*)((Pf) + (size_t)(col)[(i) + 3]  * 128);       \
    ushort4 v4  = *(const ushort4*)((Pf) + (size_t)(col)[(i) + 4]  * 128);       \
    ushort4 v5  = *(const ushort4*)((Pf) + (size_t)(col)[(i) + 5]  * 128);       \
    ushort4 v6  = *(const ushort4*)((Pf) + (size_t)(col)[(i) + 6]  * 128);       \
    ushort4 v7  = *(const ushort4*)((Pf) + (size_t)(col)[(i) + 7]  * 128);       \
    ushort4 v8  = *(const ushort4*)((Pf) + (size_t)(col)[(i) + 8]  * 128);       \
    ushort4 v9  = *(const ushort4*)((Pf) + (size_t)(col)[(i) + 9]  * 128);       \
    ushort4 v10 = *(const ushort4*)((Pf) + (size_t)(col)[(i) + 10] * 128);       \
    ushort4 v11 = *(const ushort4*)((Pf) + (size_t)(col)[(i) + 11] * 128);       \
    ushort4 v12 = *(const ushort4*)((Pf) + (size_t)(col)[(i) + 12] * 128);       \
    ushort4 v13 = *(const ushort4*)((Pf) + (size_t)(col)[(i) + 13] * 128);       \
    ushort4 v14 = *(const ushort4*)((Pf) + (size_t)(col)[(i) + 14] * 128);       \
    ushort4 v15 = *(const ushort4*)((Pf) + (size_t)(col)[(i) + 15] * 128);       \
    ax += ((bf2f(v0.x) + bf2f(v1.x)) + (bf2f(v2.x) + bf2f(v3.x)))               \
        + ((bf2f(v4.x) + bf2f(v5.x)) + (bf2f(v6.x) + bf2f(v7.x)))               \
        + ((bf2f(v8.x) + bf2f(v9.x)) + (bf2f(v10.x) + bf2f(v11.x)))             \
        + ((bf2f(v12.x) + bf2f(v13.x)) + (bf2f(v14.x) + bf2f(v15.x)));          \
    ay += ((bf2f(v0.y) + bf2f(v1.y)) + (bf2f(v2.y) + bf2f(v3.y)))               \
        + ((bf2f(v4.y) + bf2f(v5.y)) + (bf2f(v6.y) + bf2f(v7.y)))               \
        + ((bf2f(v8.y) + bf2f(v9.y)) + (bf2f(v10.y) + bf2f(v11.y)))             \
        + ((bf2f(v12.y) + bf2f(v13.y)) + (bf2f(v14.y) + bf2f(v15.y)));          \
    az += ((bf2f(v0.z) + bf2f(v1.z)) + (bf2f(v2.z) + bf2f(v3.z)))               \
        + ((bf2f(v4.z) + bf2f(v5.z)) + (bf2f(v6.z) + bf2f(v7.z)))               \
        + ((bf2f(v8.z) + bf2f(v9.z)) + (bf2f(v10.z) + bf2f(v11.z)))             \
        + ((bf2f(v12.z) + bf2f(v13.z)) + (bf2f(v14.z) + bf2f(v15.z)));          \
    aw += ((bf2f(v0.w) + bf2f(v1.w)) + (bf2f(v2.w) + bf2f(v3.w)))               \
        + ((bf2f(v4.w) + bf2f(v5.w)) + (bf2f(v6.w) + bf2f(v7.w)))               \
        + ((bf2f(v8.w) + bf2f(v9.w)) + (bf2f(v10.w) + bf2f(v11.w)))             \
        + ((bf2f(v12.w) + bf2f(v13.w)) + (bf2f(v14.w) + bf2f(v15.w)));

// Masked 8-batch tail: clamped idx + 0/1 selector, no serial dependent chain.
#define GTAIL8(Pf, col, i, end)                                                  \
    if ((i) < (end)) {                                                           \
        int cl = (end) - 1;                                                      \
        int e1 = (i) + 1 < (end) ? (i) + 1 : cl, e2 = (i) + 2 < (end) ? (i) + 2 : cl; \
        int e3 = (i) + 3 < (end) ? (i) + 3 : cl, e4 = (i) + 4 < (end) ? (i) + 4 : cl; \
        int e5 = (i) + 5 < (end) ? (i) + 5 : cl, e6 = (i) + 6 < (end) ? (i) + 6 : cl; \
        int e7 = (i) + 7 < (end) ? (i) + 7 : cl;                                 \
        float m1 = (i) + 1 < (end) ? 1.f : 0.f, m2 = (i) + 2 < (end) ? 1.f : 0.f; \
        float m3 = (i) + 3 < (end) ? 1.f : 0.f, m4 = (i) + 4 < (end) ? 1.f : 0.f; \
        float m5 = (i) + 5 < (end) ? 1.f : 0.f, m6 = (i) + 6 < (end) ? 1.f : 0.f; \
        float m7 = (i) + 7 < (end) ? 1.f : 0.f;                                  \
        ushort4 t0 = *(const ushort4*)((Pf) + (size_t)(col)[(i)] * 128);         \
        ushort4 t1 = *(const ushort4*)((Pf) + (size_t)(col)[e1] * 128);          \
        ushort4 t2 = *(const ushort4*)((Pf) + (size_t)(col)[e2] * 128);          \
        ushort4 t3 = *(const ushort4*)((Pf) + (size_t)(col)[e3] * 128);          \
        ushort4 t4 = *(const ushort4*)((Pf) + (size_t)(col)[e4] * 128);          \
        ushort4 t5 = *(const ushort4*)((Pf) + (size_t)(col)[e5] * 128);          \
        ushort4 t6 = *(const ushort4*)((Pf) + (size_t)(col)[e6] * 128);          \
        ushort4 t7 = *(const ushort4*)((Pf) + (size_t)(col)[e7] * 128);          \
        ax += bf2f(t0.x) + m1 * bf2f(t1.x) + m2 * bf2f(t2.x) + m3 * bf2f(t3.x)  \
            + m4 * bf2f(t4.x) + m5 * bf2f(t5.x) + m6 * bf2f(t6.x) + m7 * bf2f(t7.x); \
        ay += bf2f(t0.y) + m1 * bf2f(t1.y) + m2 * bf2f(t2.y) + m3 * bf2f(t3.y)  \
            + m4 * bf2f(t4.y) + m5 * bf2f(t5.y) + m6 * bf2f(t6.y) + m7 * bf2f(t7.y); \
        az += bf2f(t0.z) + m1 * bf2f(t1.z) + m2 * bf2f(t2.z) + m3 * bf2f(t3.z)  \
            + m4 * bf2f(t4.z) + m5 * bf2f(t5.z) + m6 * bf2f(t6.z) + m7 * bf2f(t7.z); \
        aw += bf2f(t0.w) + m1 * bf2f(t1.w) + m2 * bf2f(t2.w) + m3 * bf2f(t3.w)  \
            + m4 * bf2f(t4.w) + m5 * bf2f(t5.w) + m6 * bf2f(t6.w) + m7 * bf2f(t7.w); \
    }

// ---------- gather2: half-wave per row, 16-deep batches, masked tail ----------
__global__ __launch_bounds__(256, 3) void gather2_kernel(
    const int* __restrict__ rowbeg, const int* __restrict__ rowend,
    const int* __restrict__ col, const unsigned short* __restrict__ P,
    const float* __restrict__ dinv, const float* __restrict__ bias,
    float* __restrict__ OF, int N) {
    int gid = blockIdx.x * blockDim.x + threadIdx.x;
    int r = gid >> 5;
    if (r >= N) return;
    int lane = gid & 31;
    const size_t off = (size_t)lane * 4;
    const unsigned short* Pf = P + off;

    ushort4 u = *(const ushort4*)(Pf + (size_t)r * 128);
    float ax = bf2f(u.x), ay = bf2f(u.y), az = bf2f(u.z), aw = bf2f(u.w);

    int beg = rowbeg[r], end = rowend[r];
    int i = beg;
    for (; i + 15 < end; i += 16) { GLOAD16(Pf, col, i) }
    for (; i + 7 < end; i += 8) {
        ushort4 v0 = *(const ushort4*)(Pf + (size_t)col[i + 0] * 128);
        ushort4 v1 = *(const ushort4*)(Pf + (size_t)col[i + 1] * 128);
        ushort4 v2 = *(const ushort4*)(Pf + (size_t)col[i + 2] * 128);
        ushort4 v3 = *(const ushort4*)(Pf + (size_t)col[i + 3] * 128);
        ushort4 v4 = *(const ushort4*)(Pf + (size_t)col[i + 4] * 128);
        ushort4 v5 = *(const ushort4*)(Pf + (size_t)col[i + 5] * 128);
        ushort4 v6 = *(const ushort4*)(Pf + (size_t)col[i + 6] * 128);
        ushort4 v7 = *(const ushort4*)(Pf + (size_t)col[i + 7] * 128);
        ax += (bf2f(v0.x) + bf2f(v1.x)) + (bf2f(v2.x) + bf2f(v3.x))
            + (bf2f(v4.x) + bf2f(v5.x)) + (bf2f(v6.x) + bf2f(v7.x));
        ay += (bf2f(v0.y) + bf2f(v1.y)) + (bf2f(v2.y) + bf2f(v3.y))
            + (bf2f(v4.y) + bf2f(v5.y)) + (bf2f(v6.y) + bf2f(v7.y));
        az += (bf2f(v0.z) + bf2f(v1.z)) + (bf2f(v2.z) + bf2f(v3.z))
            + (bf2f(v4.z) + bf2f(v5.z)) + (bf2f(v6.z) + bf2f(v7.z));
        aw += (bf2f(v0.w) + bf2f(v1.w)) + (bf2f(v2.w) + bf2f(v3.w))
            + (bf2f(v4.w) + bf2f(v5.w)) + (bf2f(v6.w) + bf2f(v7.w));
    }
    GTAIL8(Pf, col, i, end)
    float s = dinv[r];
    float4 bb = *(const float4*)(bias + off);
    float4 o;
    o.x = fmaxf(ax * s + bb.x, 0.f);
    o.y = fmaxf(ay * s + bb.y, 0.f);
    o.z = fmaxf(az * s + bb.z, 0.f);
    o.w = fmaxf(aw * s + bb.w, 0.f);
    *(float4*)(OF + (size_t)r * 128 + off) = o;
}

// ---------- fused gather1 + GEMM1 + GEMM2, 1 half-wave per row, 16-deep ----------
__global__ __launch_bounds__(512, 3) void gemm_fused_kernel(
    const int* __restrict__ rowbeg, const int* __restrict__ rowend,
    const int* __restrict__ col, const unsigned short* __restrict__ Xs,
    const unsigned short* __restrict__ W1s, const unsigned short* __restrict__ W2s,
    const float* __restrict__ bias, const float* __restrict__ dinv,
    unsigned short* __restrict__ T, int M) {
    __shared__ unsigned short Xt[16 * XTSTRIDE];   // 4352 B: aggregated bf16 A tile
    __shared__ unsigned short Ht[16 * LDSTRIDE];   // 8448 B: H tile

    int t = threadIdx.x;
    int m0 = blockIdx.x * 16;
    int hw = t >> 5;            // half-wave 0..15 = local row
    int l  = t & 31;
    const unsigned short* Pf = Xs + (size_t)l * 4;

    {
        int r = m0 + hw;
        int rc = (r < M) ? r : (M - 1);
        ushort4 u = *(const ushort4*)(Pf + (size_t)rc * 128);   // self-loop
        float ax = bf2f(u.x), ay = bf2f(u.y), az = bf2f(u.z), aw = bf2f(u.w);
        int beg = rowbeg[rc], end = rowend[rc];
        int i = beg;
        for (; i + 15 < end; i += 16) { GLOAD16(Pf, col, i) }
        for (; i + 7 < end; i += 8) {
            ushort4 v0 = *(const ushort4*)(Pf + (size_t)col[i + 0] * 128);
            ushort4 v1 = *(const ushort4*)(Pf + (size_t)col[i + 1] * 128);
            ushort4 v2 = *(const ushort4*)(Pf + (size_t)col[i + 2] * 128);
            ushort4 v3 = *(const ushort4*)(Pf + (size_t)col[i + 3] * 128);
            ushort4 v4 = *(const ushort4*)(Pf + (size_t)col[i + 4] * 128);
            ushort4 v5 = *(const ushort4*)(Pf + (size_t)col[i + 5] * 128);
            ushort4 v6 = *(const ushort4*)(Pf + (size_t)col[i + 6] * 128);
            ushort4 v7 = *(const ushort4*)(Pf + (size_t)col[i + 7] * 128);
            ax += (bf2f(v0.x) + bf2f(v1.x)) + (bf2f(v2.x) + bf2f(v3.x))
                + (bf2f(v4.x) + bf2f(v5.x)) + (bf2f(v6.x) + bf2f(v7.x));
            ay += (bf2f(v0.y) + bf2f(v1.y)) + (bf2f(v2.y) + bf2f(v3.y))
                + (bf2f(v4.y) + bf2f(v5.y)) + (bf2f(v6.y) + bf2f(v7.y));
            az += (bf2f(v0.z) + bf2f(v1.z)) + (bf2f(v2.z) + bf2f(v3.z))
                + (bf2f(v4.z) + bf2f(v5.z)) + (bf2f(v6.z) + bf2f(v7.z));
            aw += (bf2f(v0.w) + bf2f(v1.w)) + (bf2f(v2.w) + bf2f(v3.w))
                + (bf2f(v4.w) + bf2f(v5.w)) + (bf2f(v6.w) + bf2f(v7.w));
        }
        GTAIL8(Pf, col, i, end)
        float dvr = dinv[rc];
        ushort4 o;
        o.x = f2bf(ax * dvr); o.y = f2bf(ay * dvr);
        o.z = f2bf(az * dvr); o.w = f2bf(aw * dvr);
        *(ushort4*)(Xt + hw * XTSTRIDE + l * 4) = o;
    }
    __syncthreads();

    int wave = t >> 6;          // 0..7
    int lane = t & 63;
    int mrow = lane & 15, quad = lane >> 4;

    bf16x8 a[4];
#pragma unroll
    for (int kc = 0; kc < 4; kc++)
        a[kc] = *(const bf16x8*)(Xt + mrow * XTSTRIDE + kc * 32 + quad * 8);

    float dv[4];
#pragma unroll
    for (int i2 = 0; i2 < 4; i2++) {
        int gr = m0 + quad * 4 + i2;
        dv[i2] = dinv[gr < M ? gr : M - 1];
    }

    // ---- GEMM1: 16 nt tiles split 2 per wave -> Ht ----
    const bf16x8* w1v = (const bf16x8*)W1s;
    for (int nt = wave * 2; nt < wave * 2 + 2; nt++) {
        f32x4 c = {0.f, 0.f, 0.f, 0.f};
#pragma unroll
        for (int kc = 0; kc < 4; kc++) {
            bf16x8 b = w1v[(nt * 4 + kc) * 64 + lane];
            c = __builtin_amdgcn_mfma_f32_16x16x32_bf16(a[kc], b, c, 0, 0, 0);
        }
        int colc = nt * 16 + mrow;
        float bb = bias[colc];
#pragma unroll
        for (int i2 = 0; i2 < 4; i2++) {
            float v = fmaxf(c[i2] + bb, 0.f) * dv[i2];
            Ht[(quad * 4 + i2) * LDSTRIDE + colc] = f2bf(v);
        }
    }
    __syncthreads();

    // ---- GEMM2: 8 nt tiles, 1 per wave -> T ----
    bf16x8 hh[8];
    const unsigned short* hrow = Ht + mrow * LDSTRIDE + quad * 8;
#pragma unroll
    for (int kc = 0; kc < 8; kc++) hh[kc] = *(const bf16x8*)(hrow + kc * 32);
    const bf16x8* w2v = (const bf16x8*)W2s;
    {
        int nt = wave;
        f32x4 c = {0.f, 0.f, 0.f, 0.f};
#pragma unroll
        for (int kc = 0; kc < 8; kc++) {
            bf16x8 b = w2v[(nt * 8 + kc) * 64 + lane];
            c = __builtin_amdgcn_mfma_f32_16x16x32_bf16(hh[kc], b, c, 0, 0, 0);
        }
        int colc = nt * 16 + mrow;
#pragma unroll
        for (int i2 = 0; i2 < 4; i2++) {
            int gr = m0 + quad * 4 + i2;
            if (gr < M) T[(size_t)gr * 128 + colc] = f2bf(c[i2]);
        }
    }
}

extern "C" void kernel_launch(void* const* d_in, const int* in_sizes, int n_in,
                              void* d_out, int out_size, void* d_ws, size_t ws_size,
                              hipStream_t stream) {
    const float* x  = (const float*)d_in[0];
    const int* ei   = (const int*)d_in[1];     // int32 (JAX x64 disabled)
    const float* W1 = (const float*)d_in[2];
    const float* b1 = (const float*)d_in[3];
    const float* W2 = (const float*)d_in[4];
    const float* b2 = (const float*)d_in[5];
    float* out      = (float*)d_out;

    const int N = in_sizes[0] / 128;
    const int E = in_sizes[1] / 2;
    const int* src = ei;
    const int* dst = ei + E;

    const int nbuck = (N + BMASK) >> BSHIFT;                // 391
    int cap = E / nbuck + E / (4 * nbuck) + 512;            // ~3069
    if (cap > CAPMAX) cap = CAPMAX;                         // sh_col bound

    // Workspace: dinv | Ts | Xs | W1s | W2s | rowbeg | rowend | ctrl | bbuf | col
    float* ws = (float*)d_ws;
    size_t Np = ((size_t)N + 255) & ~(size_t)255;
    float*          dinv = ws;
    unsigned short* Ts   = (unsigned short*)(dinv + Np);    // N*128 bf16
    unsigned short* Xs   = Ts + (size_t)N * 128;            // N*128 bf16
    unsigned short* W1s  = Xs + (size_t)N * 128;            // 32768
    unsigned short* W2s  = W1s + 32768;                     // 32768
    int* rowbeg = (int*)(W2s + 32768);                      // N
    int* rowend = rowbeg + Np;                              // N
    int* ctrl   = rowend + Np;                              // bcur[512]
    int* bcur   = ctrl;
    unsigned int* bbuf = (unsigned int*)(ctrl + 512);       // nbuck*cap packed
    int* col    = (int*)(bbuf + (size_t)nbuck * cap);       // nbuck*cap

    // 1. weight swizzle + ctrl zero, then CSR build (+ deterministic rank sort)
    wswz_kernel<<<256, 256, 0, stream>>>(W1, W2, W1s, W2s, ctrl);
    int nbins = (E + 2047) / 2048;                          // 391
    bin_kernel<<<nbins, 256, 0, stream>>>(src, dst, bcur, bbuf, E, cap, nbuck);
    bucket_csr_kernel<<<nbuck, 256, 0, stream>>>(bcur, bbuf, x, col, rowbeg, rowend,
                                                 dinv, Xs, N, cap);

    // 2. fused gather1 + GEMM1 + GEMM2 -> Ts (8 waves per 16-row tile)
    int mtiles = (N + 15) / 16;
    gemm_fused_kernel<<<mtiles, 512, 0, stream>>>(rowbeg, rowend, col, Xs,
                                                  W1s, W2s, b1, dinv, Ts, N);

    // 3. gather2 + fused bias/relu -> out
    int gth = N * 32;
    gather2_kernel<<<(gth + 255) / 256, 256, 0, stream>>>(rowbeg, rowend, col, Ts,
                                                          dinv, b2, out, N);
}

// Round 12
// 197.539 us; speedup vs baseline: 7.6258x; 1.0608x over previous
//
#include <hip/hip_runtime.h>

// GCN 2-layer, R25 = R18 gather structure (8-deep batches) + R24 rank-sort.
// R24 verdict: depth-16 FAILED (57.2 vs 47.2us, occ 68->38%, VGPR 44) -
// wider load window thrashes L1 (64 lines in flight/half-wave vs 32KB L1);
// R18's 47us is near the random-256B-row L2/L3 service bound (~205MB at
// ~4.5TB/s random). Rank-sort (R24) retained: bucket_csr off top-5 and
// output bit-deterministic across replays (R21 tripwire).
//   wswz(+ctrl zero) | bin | bucket_csr(rank-sort,dinv,Xs) | gemm_fused | gather2
// Lessons: no global atomic work queues (R7); no serial stragglers (R9); zero
// ALL control memory (R11); min-waves must fit live regs (R14); don't hand-
// pipeline scattered loads (R16); restructure for fat per-instr rows (R17);
// no serial dependent-load tails (R18); scatter-push dies register-starved
// (R19); atomic-ordered intermediates feeding float sums must be
// canonicalized (R21) in LDS (R22) with parallel rank-sort (R23); load-batch
// depth beyond 8 thrashes L1 and loses occupancy (R24).

typedef short bf16x8 __attribute__((ext_vector_type(8)));
typedef float f32x4 __attribute__((ext_vector_type(4)));

#define LDSTRIDE 264   // H tile: 16 rows * 264 ushort = 528 B/row, 16B-aligned
#define XTSTRIDE 136   // A tile: 16 rows * 136 ushort = 272 B/row, 16B-aligned
#define BSHIFT 7       // 128 dsts per bucket
#define BMASK 127
#define CAPMAX 3072    // sh_col capacity (ints); host cap must be <= this

__device__ inline unsigned short f2bf(float f) {          // RNE
    unsigned int u = __float_as_uint(f);
    u += 0x7FFF + ((u >> 16) & 1);
    return (unsigned short)(u >> 16);
}
__device__ inline float bf2f(unsigned short h) {
    return __uint_as_float(((unsigned int)h) << 16);
}

// ---------- W swizzle into MFMA b-frag order + ctrl zero ----------
__device__ inline void swz1(const float* W, unsigned short* Ws, int K, int N, int i) {
    int k = i / N, n = i % N;
    int KC = K >> 5;
    size_t d = ((((size_t)(n >> 4) * KC + (k >> 5)) * 64) + ((k >> 3) & 3) * 16 + (n & 15)) * 8
               + (k & 7);
    Ws[d] = f2bf(W[i]);
}
__global__ void wswz_kernel(const float* __restrict__ W1, const float* __restrict__ W2,
                            unsigned short* __restrict__ W1s, unsigned short* __restrict__ W2s,
                            int* __restrict__ ctrl) {
    int i = blockIdx.x * blockDim.x + threadIdx.x;
    if (blockIdx.x == 0) {                     // zero ALL 512 ctrl ints
        for (int j = threadIdx.x; j < 512; j += 256) ctrl[j] = 0;
    }
    if (i < 32768) swz1(W1, W1s, 128, 256, i);
    else if (i < 65536) swz1(W2, W2s, 256, 128, i - 32768);
}

// ---------- pass 1: bin edges by dst>>7 (4 B packed) ----------
__global__ __launch_bounds__(256) void bin_kernel(
    const int* __restrict__ src, const int* __restrict__ dst,
    int* __restrict__ bcur, unsigned int* __restrict__ bbuf,
    int E, int cap, int nbuck) {
    __shared__ int cnt[512];
    __shared__ int base[512];
    int t = threadIdx.x;
    for (int i = t; i < nbuck; i += 256) cnt[i] = 0;
    __syncthreads();
    int e0 = blockIdx.x * 2048;
    unsigned int p_[8];
    int b_[8];
#pragma unroll
    for (int i = 0; i < 8; i++) {
        int e = e0 + i * 256 + t;
        if (e < E) {
            int s = src[e], d = dst[e];
            b_[i] = d >> BSHIFT;
            p_[i] = ((unsigned)(d & BMASK) << 24) | (unsigned)s;   // N < 2^24
            atomicAdd(&cnt[b_[i]], 1);
        } else b_[i] = -1;
    }
    __syncthreads();
    for (int b = t; b < nbuck; b += 256) {
        int c = cnt[b];
        base[b] = (c > 0) ? atomicAdd(&bcur[b], c) : 0;
    }
    __syncthreads();
    for (int i = t; i < nbuck; i += 256) cnt[i] = 0;   // reuse as cursor
    __syncthreads();
#pragma unroll
    for (int i = 0; i < 8; i++) {
        if (b_[i] >= 0) {
            int b = b_[i];
            int p = base[b] + atomicAdd(&cnt[b], 1);
            if (p >= 0 && p < cap) bbuf[(size_t)b * cap + p] = p_[i];
        }
    }
}

// ---------- pass 2: per-bucket (128 dsts) CSR + parallel rank sort + Xs ----------
__global__ __launch_bounds__(256) void bucket_csr_kernel(
    const int* __restrict__ bcur, const unsigned int* __restrict__ bbuf,
    const float* __restrict__ x,
    int* __restrict__ col, int* __restrict__ rowbeg, int* __restrict__ rowend,
    float* __restrict__ dinv, unsigned short* __restrict__ Xs, int N, int cap) {
    __shared__ int ldeg[128];
    __shared__ int sbeg[128];
    __shared__ int lrp[256];
    __shared__ float sdv[128];
    __shared__ int sh_col[CAPMAX];               // 12288 B: packed (row<<24)|src
    int b = blockIdx.x, t = threadIdx.x;
    int cnt = min(max(bcur[b], 0), cap);
    if (t < 128) ldeg[t] = 0;
    __syncthreads();
    const unsigned int* mybuf = bbuf + (size_t)b * cap;
    for (int i = t; i < cnt; i += 256)
        atomicAdd(&ldeg[mybuf[i] >> 24], 1);
    __syncthreads();
    int v = (t < 128) ? ldeg[t] : 0;
    lrp[t] = v;
    __syncthreads();
    for (int off = 1; off < 128; off <<= 1) {    // inclusive scan (128 live)
        int u = (t >= off) ? lrp[t - off] : 0;
        __syncthreads();
        lrp[t] += u;
        __syncthreads();
    }
    int excl = lrp[t] - v;
    int gbase = b * cap;
    if (t < 128) {
        int r = b * 128 + t;
        float dv = rsqrtf((float)v + 1.0f);      // self-loop adds 1
        sdv[t] = dv;
        if (r < N) {
            rowbeg[r] = gbase + excl;
            rowend[r] = gbase + excl + v;
            dinv[r] = dv;
        }
        sbeg[t] = excl;    // segment start (stable)
        ldeg[t] = excl;    // LOCAL scatter cursor
    }
    __syncthreads();
    for (int i = t; i < cnt; i += 256) {         // scatter packed vals into LDS
        unsigned int pr = mybuf[i];
        int p = atomicAdd(&ldeg[pr >> 24], 1);
        sh_col[p] = (int)pr;                     // keep row bits for compare
    }
    __syncthreads();
    // deterministic order via PARALLEL rank sort: element i's slot =
    // segment_start + #{j: v_j < v_i} + #{j: v_j == v_i && j < i}. Equal
    // values interchangeable -> array content launch-invariant. ~deg
    // independent LDS reads per element, no dependent chain (R23 lesson).
    for (int i = t; i < cnt; i += 256) {
        int vi = sh_col[i];
        int row = ((unsigned)vi) >> 24;
        int s0 = sbeg[row];
        int s1 = ldeg[row];                      // = s0 + deg (post-scatter)
        int rank = 0;
        for (int j = s0; j < s1; j++) {
            int vj = sh_col[j];
            rank += (vj < vi || (vj == vi && j < i)) ? 1 : 0;
        }
        col[gbase + s0 + rank] = vi & 0xffffff;
    }
    // fused Xs: rows b*128..+127, coalesced ushort4
    int rbase = b * 128;
    for (int i = t; i < 128 * 32; i += 256) {
        int rl = i >> 5;
        int gr = rbase + rl;
        if (gr >= N) break;
        float s = sdv[rl];
        float4 xv = ((const float4*)x)[(size_t)gr * 32 + (i & 31)];
        ushort4 o;
        o.x = f2bf(xv.x * s); o.y = f2bf(xv.y * s);
        o.z = f2bf(xv.z * s); o.w = f2bf(xv.w * s);
        ((ushort4*)Xs)[(size_t)gr * 32 + (i & 31)] = o;
    }
}

// 8-deep batched row accumulate (R18/R25 shape: the measured sweet spot —
// 16-deep thrashed L1, R24).
#define GLOAD8(Pf, col, i)                                                       \
    {                                                                            \
        ushort4 v0 = *(const ushort4*)((Pf) + (size_t)(col)[(i) + 0] * 128);     \
        ushort4 v1 = *(const ushort4*)((Pf) + (size_t)(col)[(i) + 1] * 128);     \
        ushort4 v2 = *(const ushort4*)((Pf) + (size_t)(col)[(i) + 2] * 128);     \
        ushort4 v3 = *(const ushort4*)((Pf) + (size_t)(col)[(i) + 3] * 128);     \
        ushort4 v4 = *(const ushort4*)((Pf) + (size_t)(col)[(i) + 4] * 128);     \
        ushort4 v5 = *(const ushort4*)((Pf) + (size_t)(col)[(i) + 5] * 128);     \
        ushort4 v6 = *(const ushort4*)((Pf) + (size_t)(col)[(i) + 6] * 128);     \
        ushort4 v7 = *(const ushort4*)((Pf) + (size_t)(col)[(i) + 7] * 128);     \
        ax += (bf2f(v0.x) + bf2f(v1.x)) + (bf2f(v2.x) + bf2f(v3.x))             \
            + (bf2f(v4.x) + bf2f(v5.x)) + (bf2f(v6.x) + bf2f(v7.x));            \
        ay += (bf2f(v0.y) + bf2f(v1.y)) + (bf2f(v2.y) + bf2f(v3.y))             \
            + (bf2f(v4.y) + bf2f(v5.y)) + (bf2f(v6.y) + bf2f(v7.y));            \
        az += (bf2f(v0.z) + bf2f(v1.z)) + (bf2f(v2.z) + bf2f(v3.z))             \
            + (bf2f(v4.z) + bf2f(v5.z)) + (bf2f(v6.z) + bf2f(v7.z));            \
        aw += (bf2f(v0.w) + bf2f(v1.w)) + (bf2f(v2.w) + bf2f(v3.w))             \
            + (bf2f(v4.w) + bf2f(v5.w)) + (bf2f(v6.w) + bf2f(v7.w));            \
    }

// Masked 8-batch tail: clamped idx + 0/1 selector, no serial dependent chain.
#define GTAIL8(Pf, col, i, end)                                                  \
    if ((i) < (end)) {                                                           \
        int cl = (end) - 1;                                                      \
        int e1 = (i) + 1 < (end) ? (i) + 1 : cl, e2 = (i) + 2 < (end) ? (i) + 2 : cl; \
        int e3 = (i) + 3 < (end) ? (i) + 3 : cl, e4 = (i) + 4 < (end) ? (i) + 4 : cl; \
        int e5 = (i) + 5 < (end) ? (i) + 5 : cl, e6 = (i) + 6 < (end) ? (i) + 6 : cl; \
        int e7 = (i) + 7 < (end) ? (i) + 7 : cl;                                 \
        float m1 = (i) + 1 < (end) ? 1.f : 0.f, m2 = (i) + 2 < (end) ? 1.f : 0.f; \
        float m3 = (i) + 3 < (end) ? 1.f : 0.f, m4 = (i) + 4 < (end) ? 1.f : 0.f; \
        float m5 = (i) + 5 < (end) ? 1.f : 0.f, m6 = (i) + 6 < (end) ? 1.f : 0.f; \
        float m7 = (i) + 7 < (end) ? 1.f : 0.f;                                  \
        ushort4 t0 = *(const ushort4*)((Pf) + (size_t)(col)[(i)] * 128);         \
        ushort4 t1 = *(const ushort4*)((Pf) + (size_t)(col)[e1] * 128);          \
        ushort4 t2 = *(const ushort4*)((Pf) + (size_t)(col)[e2] * 128);          \
        ushort4 t3 = *(const ushort4*)((Pf) + (size_t)(col)[e3] * 128);          \
        ushort4 t4 = *(const ushort4*)((Pf) + (size_t)(col)[e4] * 128);          \
        ushort4 t5 = *(const ushort4*)((Pf) + (size_t)(col)[e5] * 128);          \
        ushort4 t6 = *(const ushort4*)((Pf) + (size_t)(col)[e6] * 128);          \
        ushort4 t7 = *(const ushort4*)((Pf) + (size_t)(col)[e7] * 128);          \
        ax += bf2f(t0.x) + m1 * bf2f(t1.x) + m2 * bf2f(t2.x) + m3 * bf2f(t3.x)  \
            + m4 * bf2f(t4.x) + m5 * bf2f(t5.x) + m6 * bf2f(t6.x) + m7 * bf2f(t7.x); \
        ay += bf2f(t0.y) + m1 * bf2f(t1.y) + m2 * bf2f(t2.y) + m3 * bf2f(t3.y)  \
            + m4 * bf2f(t4.y) + m5 * bf2f(t5.y) + m6 * bf2f(t6.y) + m7 * bf2f(t7.y); \
        az += bf2f(t0.z) + m1 * bf2f(t1.z) + m2 * bf2f(t2.z) + m3 * bf2f(t3.z)  \
            + m4 * bf2f(t4.z) + m5 * bf2f(t5.z) + m6 * bf2f(t6.z) + m7 * bf2f(t7.z); \
        aw += bf2f(t0.w) + m1 * bf2f(t1.w) + m2 * bf2f(t2.w) + m3 * bf2f(t3.w)  \
            + m4 * bf2f(t4.w) + m5 * bf2f(t5.w) + m6 * bf2f(t6.w) + m7 * bf2f(t7.w); \
    }

// ---------- gather2: half-wave per row, 8-deep batches, masked tail ----------
__global__ __launch_bounds__(256) void gather2_kernel(
    const int* __restrict__ rowbeg, const int* __restrict__ rowend,
    const int* __restrict__ col, const unsigned short* __restrict__ P,
    const float* __restrict__ dinv, const float* __restrict__ bias,
    float* __restrict__ OF, int N) {
    int gid = blockIdx.x * blockDim.x + threadIdx.x;
    int r = gid >> 5;
    if (r >= N) return;
    int lane = gid & 31;
    const size_t off = (size_t)lane * 4;
    const unsigned short* Pf = P + off;

    ushort4 u = *(const ushort4*)(Pf + (size_t)r * 128);
    float ax = bf2f(u.x), ay = bf2f(u.y), az = bf2f(u.z), aw = bf2f(u.w);

    int beg = rowbeg[r], end = rowend[r];
    int i = beg;
    for (; i + 7 < end; i += 8) GLOAD8(Pf, col, i)
    GTAIL8(Pf, col, i, end)
    float s = dinv[r];
    float4 bb = *(const float4*)(bias + off);
    float4 o;
    o.x = fmaxf(ax * s + bb.x, 0.f);
    o.y = fmaxf(ay * s + bb.y, 0.f);
    o.z = fmaxf(az * s + bb.z, 0.f);
    o.w = fmaxf(aw * s + bb.w, 0.f);
    *(float4*)(OF + (size_t)r * 128 + off) = o;
}

// ---------- fused gather1 + GEMM1 + GEMM2, 1 half-wave per row, 8-deep ----------
__global__ __launch_bounds__(512, 4) void gemm_fused_kernel(
    const int* __restrict__ rowbeg, const int* __restrict__ rowend,
    const int* __restrict__ col, const unsigned short* __restrict__ Xs,
    const unsigned short* __restrict__ W1s, const unsigned short* __restrict__ W2s,
    const float* __restrict__ bias, const float* __restrict__ dinv,
    unsigned short* __restrict__ T, int M) {
    __shared__ unsigned short Xt[16 * XTSTRIDE];   // 4352 B: aggregated bf16 A tile
    __shared__ unsigned short Ht[16 * LDSTRIDE];   // 8448 B: H tile

    int t = threadIdx.x;
    int m0 = blockIdx.x * 16;
    int hw = t >> 5;            // half-wave 0..15 = local row
    int l  = t & 31;
    const unsigned short* Pf = Xs + (size_t)l * 4;

    {
        int r = m0 + hw;
        int rc = (r < M) ? r : (M - 1);
        ushort4 u = *(const ushort4*)(Pf + (size_t)rc * 128);   // self-loop
        float ax = bf2f(u.x), ay = bf2f(u.y), az = bf2f(u.z), aw = bf2f(u.w);
        int beg = rowbeg[rc], end = rowend[rc];
        int i = beg;
        for (; i + 7 < end; i += 8) GLOAD8(Pf, col, i)
        GTAIL8(Pf, col, i, end)
        float dvr = dinv[rc];
        ushort4 o;
        o.x = f2bf(ax * dvr); o.y = f2bf(ay * dvr);
        o.z = f2bf(az * dvr); o.w = f2bf(aw * dvr);
        *(ushort4*)(Xt + hw * XTSTRIDE + l * 4) = o;
    }
    __syncthreads();

    int wave = t >> 6;          // 0..7
    int lane = t & 63;
    int mrow = lane & 15, quad = lane >> 4;

    bf16x8 a[4];
#pragma unroll
    for (int kc = 0; kc < 4; kc++)
        a[kc] = *(const bf16x8*)(Xt + mrow * XTSTRIDE + kc * 32 + quad * 8);

    float dv[4];
#pragma unroll
    for (int i2 = 0; i2 < 4; i2++) {
        int gr = m0 + quad * 4 + i2;
        dv[i2] = dinv[gr < M ? gr : M - 1];
    }

    // ---- GEMM1: 16 nt tiles split 2 per wave -> Ht ----
    const bf16x8* w1v = (const bf16x8*)W1s;
    for (int nt = wave * 2; nt < wave * 2 + 2; nt++) {
        f32x4 c = {0.f, 0.f, 0.f, 0.f};
#pragma unroll
        for (int kc = 0; kc < 4; kc++) {
            bf16x8 b = w1v[(nt * 4 + kc) * 64 + lane];
            c = __builtin_amdgcn_mfma_f32_16x16x32_bf16(a[kc], b, c, 0, 0, 0);
        }
        int colc = nt * 16 + mrow;
        float bb = bias[colc];
#pragma unroll
        for (int i2 = 0; i2 < 4; i2++) {
            float v = fmaxf(c[i2] + bb, 0.f) * dv[i2];
            Ht[(quad * 4 + i2) * LDSTRIDE + colc] = f2bf(v);
        }
    }
    __syncthreads();

    // ---- GEMM2: 8 nt tiles, 1 per wave -> T ----
    bf16x8 hh[8];
    const unsigned short* hrow = Ht + mrow * LDSTRIDE + quad * 8;
#pragma unroll
    for (int kc = 0; kc < 8; kc++) hh[kc] = *(const bf16x8*)(hrow + kc * 32);
    const bf16x8* w2v = (const bf16x8*)W2s;
    {
        int nt = wave;
        f32x4 c = {0.f, 0.f, 0.f, 0.f};
#pragma unroll
        for (int kc = 0; kc < 8; kc++) {
            bf16x8 b = w2v[(nt * 8 + kc) * 64 + lane];
            c = __builtin_amdgcn_mfma_f32_16x16x32_bf16(hh[kc], b, c, 0, 0, 0);
        }
        int colc = nt * 16 + mrow;
#pragma unroll
        for (int i2 = 0; i2 < 4; i2++) {
            int gr = m0 + quad * 4 + i2;
            if (gr < M) T[(size_t)gr * 128 + colc] = f2bf(c[i2]);
        }
    }
}

extern "C" void kernel_launch(void* const* d_in, const int* in_sizes, int n_in,
                              void* d_out, int out_size, void* d_ws, size_t ws_size,
                              hipStream_t stream) {
    const float* x  = (const float*)d_in[0];
    const int* ei   = (const int*)d_in[1];     // int32 (JAX x64 disabled)
    const float* W1 = (const float*)d_in[2];
    const float* b1 = (const float*)d_in[3];
    const float* W2 = (const float*)d_in[4];
    const float* b2 = (const float*)d_in[5];
    float* out      = (float*)d_out;

    const int N = in_sizes[0] / 128;
    const int E = in_sizes[1] / 2;
    const int* src = ei;
    const int* dst = ei + E;

    const int nbuck = (N + BMASK) >> BSHIFT;                // 391
    int cap = E / nbuck + E / (4 * nbuck) + 512;            // ~3069
    if (cap > CAPMAX) cap = CAPMAX;                         // sh_col bound

    // Workspace: dinv | Ts | Xs | W1s | W2s | rowbeg | rowend | ctrl | bbuf | col
    float* ws = (float*)d_ws;
    size_t Np = ((size_t)N + 255) & ~(size_t)255;
    float*          dinv = ws;
    unsigned short* Ts   = (unsigned short*)(dinv + Np);    // N*128 bf16
    unsigned short* Xs   = Ts + (size_t)N * 128;            // N*128 bf16
    unsigned short* W1s  = Xs + (size_t)N * 128;            // 32768
    unsigned short* W2s  = W1s + 32768;                     // 32768
    int* rowbeg = (int*)(W2s + 32768);                      // N
    int* rowend = rowbeg + Np;                              // N
    int* ctrl   = rowend + Np;                              // bcur[512]
    int* bcur   = ctrl;
    unsigned int* bbuf = (unsigned int*)(ctrl + 512);       // nbuck*cap packed
    int* col    = (int*)(bbuf + (size_t)nbuck * cap);       // nbuck*cap

    // 1. weight swizzle + ctrl zero, then CSR build (+ deterministic rank sort)
    wswz_kernel<<<256, 256, 0, stream>>>(W1, W2, W1s, W2s, ctrl);
    int nbins = (E + 2047) / 2048;                          // 391
    bin_kernel<<<nbins, 256, 0, stream>>>(src, dst, bcur, bbuf, E, cap, nbuck);
    bucket_csr_kernel<<<nbuck, 256, 0, stream>>>(bcur, bbuf, x, col, rowbeg, rowend,
                                                 dinv, Xs, N, cap);

    // 2. fused gather1 + GEMM1 + GEMM2 -> Ts (8 waves per 16-row tile)
    int mtiles = (N + 15) / 16;
    gemm_fused_kernel<<<mtiles, 512, 0, stream>>>(rowbeg, rowend, col, Xs,
                                                  W1s, W2s, b1, dinv, Ts, N);

    // 3. gather2 + fused bias/relu -> out
    int gth = N * 32;
    gather2_kernel<<<(gth + 255) / 256, 256, 0, stream>>>(rowbeg, rowend, col, Ts,
                                                          dinv, b2, out, N);
}